// Round 1
// baseline (805.626 us; speedup 1.0000x reference)
//
#include <hip/hip_runtime.h>

#define N_NODES 50000
#define N_EDGES 800000
#define N_GRAPHS 128
#define IN_CH 16
#define HIDDEN 64
#define OUT_CH 2

// ---------------- degree / normalization ----------------

__global__ void deg_init_kernel(float* __restrict__ deg) {
    int i = blockIdx.x * blockDim.x + threadIdx.x;
    if (i < N_NODES) deg[i] = 1.0f;  // self-loop contributes 1 to every node
}

__global__ void deg_accum_kernel(const int* __restrict__ dst, float* __restrict__ deg) {
    int e = blockIdx.x * blockDim.x + threadIdx.x;
    if (e < N_EDGES) {
        int d = dst[e];
        if (d >= 0 && d < N_NODES) atomicAdd(&deg[d], 1.0f);
    }
}

__global__ void dinv_kernel(float* __restrict__ deg) {
    int i = blockIdx.x * blockDim.x + threadIdx.x;
    if (i < N_NODES) deg[i] = rsqrtf(deg[i]);  // deg >= 1 always
}

// ---------------- dense linear layers ----------------

// h[n][c] = sum_k x[n][k] * W[k][c], K=16. Block = 4 nodes x 64 ch.
__global__ void gemm1_kernel(const float* __restrict__ x, const float* __restrict__ W,
                             float* __restrict__ h) {
    __shared__ float sW[IN_CH * HIDDEN];  // 4 KB
    int t = threadIdx.x;
    for (int i = t; i < IN_CH * HIDDEN; i += 256) sW[i] = W[i];
    __syncthreads();
    int n = blockIdx.x * 4 + (t >> 6);
    if (n >= N_NODES) return;
    int c = t & 63;
    const float* xr = x + n * IN_CH;
    float acc = 0.0f;
#pragma unroll
    for (int k = 0; k < IN_CH; k++) acc += xr[k] * sW[k * HIDDEN + c];
    h[n * HIDDEN + c] = acc;
}

// h[n][c] = sum_k a[n][k] * W[k][c], K=64. Block = 4 nodes x 64 ch, rows in LDS.
__global__ void gemm2_kernel(const float* __restrict__ a, const float* __restrict__ W,
                             float* __restrict__ h) {
    __shared__ float sW[HIDDEN * HIDDEN];  // 16 KB
    __shared__ float sx[4 * HIDDEN];       // 1 KB
    int t = threadIdx.x;
    for (int i = t; i < HIDDEN * HIDDEN; i += 256) sW[i] = W[i];
    int n0 = blockIdx.x * 4;
    long long gidx = (long long)n0 * HIDDEN + t;
    sx[t] = (gidx < (long long)N_NODES * HIDDEN) ? a[gidx] : 0.0f;
    __syncthreads();
    int r = t >> 6;
    int n = n0 + r;
    if (n >= N_NODES) return;
    int c = t & 63;
    float acc = 0.0f;
#pragma unroll
    for (int k = 0; k < HIDDEN; k++) acc += sx[r * HIDDEN + k] * sW[k * HIDDEN + c];
    h[n * HIDDEN + c] = acc;
}

// ---------------- edge scatter (message passing) ----------------

// One wave per edge, lane = channel: contiguous 256B atomic row per wave.
__global__ void scatter_kernel(const int* __restrict__ src, const int* __restrict__ dst,
                               const float* __restrict__ dinv, const float* __restrict__ h,
                               float* __restrict__ outb) {
    int t = threadIdx.x;
    int e = blockIdx.x * 4 + (t >> 6);
    if (e >= N_EDGES) return;
    int s = src[e];
    int d = dst[e];
    if ((unsigned)s >= N_NODES || (unsigned)d >= N_NODES) return;
    int c = t & 63;
    float norm = dinv[s] * dinv[d];
    atomicAdd(&outb[d * HIDDEN + c], h[s * HIDDEN + c] * norm);
}

// buf = relu(buf + h*dinv^2 + b)   (self-loop term + bias + activation), in place
__global__ void finalize_kernel(float* __restrict__ buf, const float* __restrict__ h,
                                const float* __restrict__ dinv, const float* __restrict__ b) {
    int i = blockIdx.x * blockDim.x + threadIdx.x;
    if (i >= N_NODES * HIDDEN) return;
    int n = i >> 6;
    int c = i & 63;
    float di = dinv[n];
    float v = buf[i] + h[i] * di * di + b[c];
    buf[i] = v > 0.0f ? v : 0.0f;
}

// ---------------- pooling + head ----------------

__global__ void pool_kernel(const float* __restrict__ act, const int* __restrict__ batch,
                            float* __restrict__ sums, float* __restrict__ cnt) {
    int t = threadIdx.x;
    int n = blockIdx.x * 4 + (t >> 6);
    if (n >= N_NODES) return;
    int c = t & 63;
    int g = batch[n];
    if ((unsigned)g >= N_GRAPHS) return;
    atomicAdd(&sums[g * HIDDEN + c], act[n * HIDDEN + c]);
    if (c == 0) atomicAdd(&cnt[g], 1.0f);
}

__global__ void head_kernel(const float* __restrict__ sums, const float* __restrict__ cnt,
                            const float* __restrict__ Wc, const float* __restrict__ bc,
                            float* __restrict__ out) {
    int t = blockIdx.x * blockDim.x + threadIdx.x;
    if (t >= N_GRAPHS * OUT_CH) return;
    int g = t >> 1;
    int o = t & 1;
    float inv = 1.0f / fmaxf(cnt[g], 1.0f);
    float acc = bc[o];
#pragma unroll
    for (int k = 0; k < HIDDEN; k++) acc += sums[g * HIDDEN + k] * inv * Wc[k * OUT_CH + o];
    out[t] = acc;
}

// ---------------- launch ----------------

extern "C" void kernel_launch(void* const* d_in, const int* in_sizes, int n_in,
                              void* d_out, int out_size, void* d_ws, size_t ws_size,
                              hipStream_t stream) {
    const float* x  = (const float*)d_in[0];      // [N_NODES, IN_CH]
    const int* ei   = (const int*)d_in[1];        // [2, N_EDGES]
    const int* bat  = (const int*)d_in[2];        // [N_NODES]
    const float* W1 = (const float*)d_in[3];      // [IN_CH, HIDDEN]
    const float* b1 = (const float*)d_in[4];      // [HIDDEN]
    const float* W2 = (const float*)d_in[5];      // [HIDDEN, HIDDEN]
    const float* b2 = (const float*)d_in[6];      // [HIDDEN]
    const float* Wc = (const float*)d_in[7];      // [HIDDEN, OUT_CH]
    const float* bc = (const float*)d_in[8];      // [OUT_CH]
    float* out = (float*)d_out;                   // [N_GRAPHS, OUT_CH]

    const int* src = ei;
    const int* dst = ei + N_EDGES;

    // workspace carve-up (floats), 256B-aligned regions
    char* ws = (char*)d_ws;
    size_t off = 0;
    auto carve = [&](size_t nbytes) {
        char* p = ws + off;
        off += (nbytes + 255) & ~(size_t)255;
        return p;
    };
    float* deg  = (float*)carve(N_NODES * sizeof(float));            // deg -> dinv in place
    float* bufA = (float*)carve((size_t)N_NODES * HIDDEN * sizeof(float));  // dense h
    float* bufB = (float*)carve((size_t)N_NODES * HIDDEN * sizeof(float));  // scatter acc / act
    float* sums = (float*)carve(N_GRAPHS * HIDDEN * sizeof(float));
    float* cnt  = (float*)carve(N_GRAPHS * sizeof(float));
    (void)ws_size;

    const int nodeBlocks  = (N_NODES + 255) / 256;
    const int edgeBlocks  = (N_EDGES + 255) / 256;
    const int waveEdgeBlk = (N_EDGES + 3) / 4;    // 4 edges (waves) per block
    const int waveNodeBlk = (N_NODES + 3) / 4;
    const int featBlocks  = (N_NODES * HIDDEN + 255) / 256;

    // normalization
    deg_init_kernel<<<nodeBlocks, 256, 0, stream>>>(deg);
    deg_accum_kernel<<<edgeBlocks, 256, 0, stream>>>(dst, deg);
    dinv_kernel<<<nodeBlocks, 256, 0, stream>>>(deg);

    // layer 1
    gemm1_kernel<<<waveNodeBlk, 256, 0, stream>>>(x, W1, bufA);
    hipMemsetAsync(bufB, 0, (size_t)N_NODES * HIDDEN * sizeof(float), stream);
    scatter_kernel<<<waveEdgeBlk, 256, 0, stream>>>(src, dst, deg, bufA, bufB);
    finalize_kernel<<<featBlocks, 256, 0, stream>>>(bufB, bufA, deg, b1);

    // layer 2
    gemm2_kernel<<<waveNodeBlk, 256, 0, stream>>>(bufB, W2, bufA);
    hipMemsetAsync(bufB, 0, (size_t)N_NODES * HIDDEN * sizeof(float), stream);
    scatter_kernel<<<waveEdgeBlk, 256, 0, stream>>>(src, dst, deg, bufA, bufB);
    finalize_kernel<<<featBlocks, 256, 0, stream>>>(bufB, bufA, deg, b2);

    // pool + head (sums and cnt are contiguous in ws -> single memset)
    hipMemsetAsync(sums, 0, (N_GRAPHS * HIDDEN + N_GRAPHS) * sizeof(float) + 256, stream);
    pool_kernel<<<waveNodeBlk, 256, 0, stream>>>(bufB, bat, sums, cnt);
    head_kernel<<<1, 256, 0, stream>>>(sums, cnt, Wc, bc, out);
}

// Round 2
// 568.413 us; speedup vs baseline: 1.4173x; 1.4173x over previous
//
#include <hip/hip_runtime.h>

#define N_NODES 50000
#define N_EDGES 800000
#define N_GRAPHS 128
#define IN_CH 16
#define HIDDEN 64
#define OUT_CH 2
#define POOL_CHUNK 128  // nodes per pool block; batch is sorted -> ~1-2 graphs/chunk

// ---------------- degree / normalization ----------------

__global__ void deg_init_kernel(float* __restrict__ deg) {
    int i = blockIdx.x * blockDim.x + threadIdx.x;
    if (i < N_NODES) deg[i] = 1.0f;  // self-loop contributes 1 to every node
}

__global__ void deg_accum_kernel(const int* __restrict__ dst, float* __restrict__ deg) {
    int e = blockIdx.x * blockDim.x + threadIdx.x;
    if (e < N_EDGES) {
        int d = dst[e];
        if (d >= 0 && d < N_NODES) atomicAdd(&deg[d], 1.0f);
    }
}

__global__ void dinv_kernel(float* __restrict__ deg) {
    int i = blockIdx.x * blockDim.x + threadIdx.x;
    if (i < N_NODES) deg[i] = rsqrtf(deg[i]);  // deg >= 1 always
}

// ---------------- dense linear layers ----------------

// h[n][c] = sum_k x[n][k] * W[k][c], K=16. Block = 4 nodes x 64 ch.
__global__ void gemm1_kernel(const float* __restrict__ x, const float* __restrict__ W,
                             float* __restrict__ h) {
    __shared__ float sW[IN_CH * HIDDEN];  // 4 KB
    int t = threadIdx.x;
    for (int i = t; i < IN_CH * HIDDEN; i += 256) sW[i] = W[i];
    __syncthreads();
    int n = blockIdx.x * 4 + (t >> 6);
    if (n >= N_NODES) return;
    int c = t & 63;
    const float* xr = x + n * IN_CH;
    float acc = 0.0f;
#pragma unroll
    for (int k = 0; k < IN_CH; k++) acc += xr[k] * sW[k * HIDDEN + c];
    h[n * HIDDEN + c] = acc;
}

// h[n][c] = sum_k a[n][k] * W[k][c], K=64. Block = 4 nodes x 64 ch, rows in LDS.
__global__ void gemm2_kernel(const float* __restrict__ a, const float* __restrict__ W,
                             float* __restrict__ h) {
    __shared__ float sW[HIDDEN * HIDDEN];  // 16 KB
    __shared__ float sx[4 * HIDDEN];       // 1 KB
    int t = threadIdx.x;
    for (int i = t; i < HIDDEN * HIDDEN; i += 256) sW[i] = W[i];
    int n0 = blockIdx.x * 4;
    long long gidx = (long long)n0 * HIDDEN + t;
    sx[t] = (gidx < (long long)N_NODES * HIDDEN) ? a[gidx] : 0.0f;
    __syncthreads();
    int r = t >> 6;
    int n = n0 + r;
    if (n >= N_NODES) return;
    int c = t & 63;
    float acc = 0.0f;
#pragma unroll
    for (int k = 0; k < HIDDEN; k++) acc += sx[r * HIDDEN + k] * sW[k * HIDDEN + c];
    h[n * HIDDEN + c] = acc;
}

// ---------------- edge scatter (message passing) ----------------

// One wave per edge, lane = channel: contiguous 256B atomic row per wave.
__global__ void scatter_kernel(const int* __restrict__ src, const int* __restrict__ dst,
                               const float* __restrict__ dinv, const float* __restrict__ h,
                               float* __restrict__ outb) {
    int t = threadIdx.x;
    int e = blockIdx.x * 4 + (t >> 6);
    if (e >= N_EDGES) return;
    int s = src[e];
    int d = dst[e];
    if ((unsigned)s >= N_NODES || (unsigned)d >= N_NODES) return;
    int c = t & 63;
    float norm = dinv[s] * dinv[d];
    atomicAdd(&outb[d * HIDDEN + c], h[s * HIDDEN + c] * norm);
}

// buf = relu(buf + h*dinv^2 + b)   (self-loop term + bias + activation), in place
__global__ void finalize_kernel(float* __restrict__ buf, const float* __restrict__ h,
                                const float* __restrict__ dinv, const float* __restrict__ b) {
    int i = blockIdx.x * blockDim.x + threadIdx.x;
    if (i >= N_NODES * HIDDEN) return;
    int n = i >> 6;
    int c = i & 63;
    float di = dinv[n];
    float v = buf[i] + h[i] * di * di + b[c];
    buf[i] = v > 0.0f ? v : 0.0f;
}

// ---------------- pooling + head ----------------

// batch is sorted: run-length accumulate per thread, flush one atomic per
// graph-run. Lane = channel, 4 rows in flight, chunk of POOL_CHUNK nodes/block.
__global__ void pool_kernel(const float* __restrict__ act, const int* __restrict__ batch,
                            float* __restrict__ sums, float* __restrict__ cnt) {
    int t = threadIdx.x;
    int c = t & 63;
    int r = t >> 6;  // 0..3
    int base = blockIdx.x * POOL_CHUNK;
    int gcur = -1;
    float acc = 0.0f;
    float cacc = 0.0f;
    for (int i = r; i < POOL_CHUNK; i += 4) {
        int n = base + i;
        if (n >= N_NODES) break;
        int g = batch[n];
        if ((unsigned)g >= N_GRAPHS) continue;
        if (g != gcur) {
            if (gcur >= 0) {
                atomicAdd(&sums[gcur * HIDDEN + c], acc);
                if (c == 0) atomicAdd(&cnt[gcur], cacc);
            }
            gcur = g;
            acc = 0.0f;
            cacc = 0.0f;
        }
        acc += act[n * HIDDEN + c];
        cacc += 1.0f;
    }
    if (gcur >= 0) {
        atomicAdd(&sums[gcur * HIDDEN + c], acc);
        if (c == 0) atomicAdd(&cnt[gcur], cacc);
    }
}

__global__ void head_kernel(const float* __restrict__ sums, const float* __restrict__ cnt,
                            const float* __restrict__ Wc, const float* __restrict__ bc,
                            float* __restrict__ out) {
    int t = blockIdx.x * blockDim.x + threadIdx.x;
    if (t >= N_GRAPHS * OUT_CH) return;
    int g = t >> 1;
    int o = t & 1;
    float inv = 1.0f / fmaxf(cnt[g], 1.0f);
    float acc = bc[o];
#pragma unroll
    for (int k = 0; k < HIDDEN; k++) acc += sums[g * HIDDEN + k] * inv * Wc[k * OUT_CH + o];
    out[t] = acc;
}

// ---------------- launch ----------------

extern "C" void kernel_launch(void* const* d_in, const int* in_sizes, int n_in,
                              void* d_out, int out_size, void* d_ws, size_t ws_size,
                              hipStream_t stream) {
    const float* x  = (const float*)d_in[0];      // [N_NODES, IN_CH]
    const int* ei   = (const int*)d_in[1];        // [2, N_EDGES]
    const int* bat  = (const int*)d_in[2];        // [N_NODES]
    const float* W1 = (const float*)d_in[3];      // [IN_CH, HIDDEN]
    const float* b1 = (const float*)d_in[4];      // [HIDDEN]
    const float* W2 = (const float*)d_in[5];      // [HIDDEN, HIDDEN]
    const float* b2 = (const float*)d_in[6];      // [HIDDEN]
    const float* Wc = (const float*)d_in[7];      // [HIDDEN, OUT_CH]
    const float* bc = (const float*)d_in[8];      // [OUT_CH]
    float* out = (float*)d_out;                   // [N_GRAPHS, OUT_CH]

    const int* src = ei;
    const int* dst = ei + N_EDGES;

    // workspace carve-up (floats), 256B-aligned regions
    char* ws = (char*)d_ws;
    size_t off = 0;
    auto carve = [&](size_t nbytes) {
        char* p = ws + off;
        off += (nbytes + 255) & ~(size_t)255;
        return p;
    };
    float* deg  = (float*)carve(N_NODES * sizeof(float));            // deg -> dinv in place
    float* bufA = (float*)carve((size_t)N_NODES * HIDDEN * sizeof(float));  // dense h
    float* bufB = (float*)carve((size_t)N_NODES * HIDDEN * sizeof(float));  // scatter acc / act
    float* sums = (float*)carve(N_GRAPHS * HIDDEN * sizeof(float));
    float* cnt  = (float*)carve(N_GRAPHS * sizeof(float));
    (void)ws_size;

    const int nodeBlocks  = (N_NODES + 255) / 256;
    const int edgeBlocks  = (N_EDGES + 255) / 256;
    const int waveEdgeBlk = (N_EDGES + 3) / 4;    // 4 edges (waves) per block
    const int waveNodeBlk = (N_NODES + 3) / 4;
    const int featBlocks  = (N_NODES * HIDDEN + 255) / 256;
    const int poolBlocks  = (N_NODES + POOL_CHUNK - 1) / POOL_CHUNK;

    // normalization
    deg_init_kernel<<<nodeBlocks, 256, 0, stream>>>(deg);
    deg_accum_kernel<<<edgeBlocks, 256, 0, stream>>>(dst, deg);
    dinv_kernel<<<nodeBlocks, 256, 0, stream>>>(deg);

    // layer 1
    gemm1_kernel<<<waveNodeBlk, 256, 0, stream>>>(x, W1, bufA);
    hipMemsetAsync(bufB, 0, (size_t)N_NODES * HIDDEN * sizeof(float), stream);
    scatter_kernel<<<waveEdgeBlk, 256, 0, stream>>>(src, dst, deg, bufA, bufB);
    finalize_kernel<<<featBlocks, 256, 0, stream>>>(bufB, bufA, deg, b1);

    // layer 2
    gemm2_kernel<<<waveNodeBlk, 256, 0, stream>>>(bufB, W2, bufA);
    hipMemsetAsync(bufB, 0, (size_t)N_NODES * HIDDEN * sizeof(float), stream);
    scatter_kernel<<<waveEdgeBlk, 256, 0, stream>>>(src, dst, deg, bufA, bufB);
    finalize_kernel<<<featBlocks, 256, 0, stream>>>(bufB, bufA, deg, b2);

    // pool + head (sums and cnt are contiguous in ws -> single memset)
    hipMemsetAsync(sums, 0, (N_GRAPHS * HIDDEN + N_GRAPHS) * sizeof(float) + 256, stream);
    pool_kernel<<<poolBlocks, 256, 0, stream>>>(bufB, bat, sums, cnt);
    head_kernel<<<1, 256, 0, stream>>>(sums, cnt, Wc, bc, out);
}

// Round 3
// 311.760 us; speedup vs baseline: 2.5841x; 1.8232x over previous
//
#include <hip/hip_runtime.h>

#define N_NODES 50000
#define N_EDGES 800000
#define N_GRAPHS 128
#define IN_CH 16
#define HIDDEN 64
#define OUT_CH 2
#define POOL_CHUNK 128
#define SCAN_B 256
#define N_SCAN_BLOCKS ((N_NODES + SCAN_B - 1) / SCAN_B)   // 196 (must be <= 256)

// ---------------- CSR build ----------------

__global__ void hist_kernel(const int* __restrict__ dst, int* __restrict__ cnt) {
    int e = blockIdx.x * blockDim.x + threadIdx.x;
    if (e < N_EDGES) {
        int d = dst[e];
        if ((unsigned)d < N_NODES) atomicAdd(&cnt[d], 1);
    }
}

__global__ void dinv_kernel(const int* __restrict__ cnt, float* __restrict__ dinv) {
    int i = blockIdx.x * blockDim.x + threadIdx.x;
    if (i < N_NODES) dinv[i] = rsqrtf((float)(cnt[i] + 1));  // +1 self-loop
}

// per-block sums of cnt
__global__ void scanA_kernel(const int* __restrict__ cnt, int* __restrict__ bsum) {
    __shared__ int s[SCAN_B];
    int t = threadIdx.x;
    int idx = blockIdx.x * SCAN_B + t;
    s[t] = (idx < N_NODES) ? cnt[idx] : 0;
    __syncthreads();
    for (int off = SCAN_B / 2; off > 0; off >>= 1) {
        if (t < off) s[t] += s[t + off];
        __syncthreads();
    }
    if (t == 0) bsum[blockIdx.x] = s[0];
}

// exclusive scan of block sums (single block; N_SCAN_BLOCKS <= 256)
__global__ void scanB_kernel(const int* __restrict__ bsum, int* __restrict__ boff) {
    __shared__ int s[SCAN_B];
    int t = threadIdx.x;
    int v = (t < N_SCAN_BLOCKS) ? bsum[t] : 0;
    s[t] = v;
    __syncthreads();
    for (int off = 1; off < SCAN_B; off <<= 1) {
        int u = (t >= off) ? s[t - off] : 0;
        __syncthreads();
        s[t] += u;
        __syncthreads();
    }
    if (t < N_SCAN_BLOCKS) boff[t] = s[t] - v;  // exclusive
}

// rowptr[i] = exclusive prefix of cnt
__global__ void scanC_kernel(const int* __restrict__ cnt, const int* __restrict__ boff,
                             int* __restrict__ rowptr) {
    __shared__ int s[SCAN_B];
    int t = threadIdx.x;
    int idx = blockIdx.x * SCAN_B + t;
    int v = (idx < N_NODES) ? cnt[idx] : 0;
    s[t] = v;
    __syncthreads();
    for (int off = 1; off < SCAN_B; off <<= 1) {
        int u = (t >= off) ? s[t - off] : 0;
        __syncthreads();
        s[t] += u;
        __syncthreads();
    }
    if (idx < N_NODES) rowptr[idx] = boff[blockIdx.x] + s[t] - v;
}

// fill: mutates rowptr (cursor); after this, rowptr[d] = row_end(d).
// gather kernels recover start = rowptr[d] - cnt[d].
__global__ void fill_kernel(const int* __restrict__ src, const int* __restrict__ dst,
                            int* __restrict__ rowptr, int* __restrict__ csr_src) {
    int e = blockIdx.x * blockDim.x + threadIdx.x;
    if (e < N_EDGES) {
        int d = dst[e];
        if ((unsigned)d < N_NODES) {
            int pos = atomicAdd(&rowptr[d], 1);
            csr_src[pos] = src[e];
        }
    }
}

// ---------------- aggregation (gather form, no atomics) ----------------

// agg1[n][0:16] = dinv[n]*sum_{s in N(n)} dinv[s]*x[s][:] + dinv[n]^2 * x[n][:]
// one wave per node; lane = c + 16*j, j in 0..3 processes every 4th edge.
__global__ void agg1_kernel(const float* __restrict__ x, const int* __restrict__ csr_src,
                            const int* __restrict__ rowend, const int* __restrict__ cnt,
                            const float* __restrict__ dinv, float* __restrict__ agg) {
    int t = threadIdx.x;
    int n = blockIdx.x * 4 + (t >> 6);
    if (n >= N_NODES) return;
    int lane = t & 63;
    int c = lane & 15;
    int j = lane >> 4;
    int len = cnt[n];
    int start = rowend[n] - len;
    float acc = 0.0f;
    for (int i = j; i < len; i += 4) {
        int s = csr_src[start + i];
        acc += dinv[s] * x[s * IN_CH + c];
    }
    acc += __shfl_xor(acc, 16, 64);
    acc += __shfl_xor(acc, 32, 64);
    if (j == 0) {
        float dn = dinv[n];
        agg[n * IN_CH + c] = dn * acc + dn * dn * x[n * IN_CH + c];
    }
}

// agg[n][0:64], one wave per node, lane = channel; 2-way unroll for ILP.
__global__ void agg2_kernel(const float* __restrict__ h, const int* __restrict__ csr_src,
                            const int* __restrict__ rowend, const int* __restrict__ cnt,
                            const float* __restrict__ dinv, float* __restrict__ agg) {
    int t = threadIdx.x;
    int n = blockIdx.x * 4 + (t >> 6);
    if (n >= N_NODES) return;
    int c = t & 63;
    int len = cnt[n];
    int start = rowend[n] - len;
    float acc0 = 0.0f, acc1 = 0.0f;
    int i = 0;
    for (; i + 1 < len; i += 2) {
        int s0 = csr_src[start + i];
        int s1 = csr_src[start + i + 1];
        float d0 = dinv[s0], d1 = dinv[s1];
        acc0 += d0 * h[s0 * HIDDEN + c];
        acc1 += d1 * h[s1 * HIDDEN + c];
    }
    if (i < len) {
        int s0 = csr_src[start + i];
        acc0 += dinv[s0] * h[s0 * HIDDEN + c];
    }
    float dn = dinv[n];
    agg[n * HIDDEN + c] = dn * (acc0 + acc1) + dn * dn * h[n * HIDDEN + c];
}

// ---------------- dense linear layers (bias + relu fused) ----------------

// h[n][c] = relu(sum_k agg[n][k]*W[k][c] + b[c]), K=16. Block = 4 nodes x 64 ch.
__global__ void gemm1_relu_kernel(const float* __restrict__ a, const float* __restrict__ W,
                                  const float* __restrict__ b, float* __restrict__ h) {
    __shared__ float sW[IN_CH * HIDDEN];  // 4 KB
    __shared__ float sx[4 * IN_CH];
    int t = threadIdx.x;
    for (int i = t; i < IN_CH * HIDDEN; i += 256) sW[i] = W[i];
    int n0 = blockIdx.x * 4;
    if (t < 4 * IN_CH) {
        long long gidx = (long long)n0 * IN_CH + t;
        sx[t] = (gidx < (long long)N_NODES * IN_CH) ? a[gidx] : 0.0f;
    }
    __syncthreads();
    int n = n0 + (t >> 6);
    if (n >= N_NODES) return;
    int r = t >> 6;
    int c = t & 63;
    float acc = b[c];
#pragma unroll
    for (int k = 0; k < IN_CH; k++) acc += sx[r * IN_CH + k] * sW[k * HIDDEN + c];
    h[n * HIDDEN + c] = acc > 0.0f ? acc : 0.0f;
}

// h[n][c] = relu(sum_k a[n][k]*W[k][c] + b[c]), K=64. In-place safe (block-local rows).
__global__ void gemm2_relu_kernel(const float* __restrict__ a, const float* __restrict__ W,
                                  const float* __restrict__ b, float* __restrict__ h) {
    __shared__ float sW[HIDDEN * HIDDEN];  // 16 KB
    __shared__ float sx[4 * HIDDEN];       // 1 KB
    int t = threadIdx.x;
    for (int i = t; i < HIDDEN * HIDDEN; i += 256) sW[i] = W[i];
    int n0 = blockIdx.x * 4;
    long long gidx = (long long)n0 * HIDDEN + t;
    sx[t] = (gidx < (long long)N_NODES * HIDDEN) ? a[gidx] : 0.0f;
    __syncthreads();
    int r = t >> 6;
    int n = n0 + r;
    if (n >= N_NODES) return;
    int c = t & 63;
    float acc = b[c];
#pragma unroll
    for (int k = 0; k < HIDDEN; k++) acc += sx[r * HIDDEN + k] * sW[k * HIDDEN + c];
    h[n * HIDDEN + c] = acc > 0.0f ? acc : 0.0f;
}

// ---------------- pooling + head ----------------

__global__ void pool_kernel(const float* __restrict__ act, const int* __restrict__ batch,
                            float* __restrict__ sums, float* __restrict__ cntg) {
    int t = threadIdx.x;
    int c = t & 63;
    int r = t >> 6;
    int base = blockIdx.x * POOL_CHUNK;
    int gcur = -1;
    float acc = 0.0f;
    float cacc = 0.0f;
    for (int i = r; i < POOL_CHUNK; i += 4) {
        int n = base + i;
        if (n >= N_NODES) break;
        int g = batch[n];
        if ((unsigned)g >= N_GRAPHS) continue;
        if (g != gcur) {
            if (gcur >= 0) {
                atomicAdd(&sums[gcur * HIDDEN + c], acc);
                if (c == 0) atomicAdd(&cntg[gcur], cacc);
            }
            gcur = g;
            acc = 0.0f;
            cacc = 0.0f;
        }
        acc += act[n * HIDDEN + c];
        cacc += 1.0f;
    }
    if (gcur >= 0) {
        atomicAdd(&sums[gcur * HIDDEN + c], acc);
        if (c == 0) atomicAdd(&cntg[gcur], cacc);
    }
}

__global__ void head_kernel(const float* __restrict__ sums, const float* __restrict__ cntg,
                            const float* __restrict__ Wc, const float* __restrict__ bc,
                            float* __restrict__ out) {
    int t = blockIdx.x * blockDim.x + threadIdx.x;
    if (t >= N_GRAPHS * OUT_CH) return;
    int g = t >> 1;
    int o = t & 1;
    float inv = 1.0f / fmaxf(cntg[g], 1.0f);
    float acc = bc[o];
#pragma unroll
    for (int k = 0; k < HIDDEN; k++) acc += sums[g * HIDDEN + k] * inv * Wc[k * OUT_CH + o];
    out[t] = acc;
}

// ---------------- launch ----------------

extern "C" void kernel_launch(void* const* d_in, const int* in_sizes, int n_in,
                              void* d_out, int out_size, void* d_ws, size_t ws_size,
                              hipStream_t stream) {
    const float* x  = (const float*)d_in[0];      // [N_NODES, IN_CH]
    const int* ei   = (const int*)d_in[1];        // [2, N_EDGES]
    const int* bat  = (const int*)d_in[2];        // [N_NODES]
    const float* W1 = (const float*)d_in[3];
    const float* b1 = (const float*)d_in[4];
    const float* W2 = (const float*)d_in[5];
    const float* b2 = (const float*)d_in[6];
    const float* Wc = (const float*)d_in[7];
    const float* bc = (const float*)d_in[8];
    float* out = (float*)d_out;

    const int* src = ei;
    const int* dst = ei + N_EDGES;

    char* ws = (char*)d_ws;
    size_t off = 0;
    auto carve = [&](size_t nbytes) {
        char* p = ws + off;
        off += (nbytes + 255) & ~(size_t)255;
        return p;
    };
    int*   cnt    = (int*)carve(N_NODES * sizeof(int));
    float* dinv   = (float*)carve(N_NODES * sizeof(float));
    int*   rowptr = (int*)carve(N_NODES * sizeof(int));     // -> row_end after fill
    int*   bsum   = (int*)carve(N_SCAN_BLOCKS * sizeof(int));
    int*   boff   = (int*)carve(N_SCAN_BLOCKS * sizeof(int));
    int*   csr    = (int*)carve(N_EDGES * sizeof(int));
    float* agg1   = (float*)carve((size_t)N_NODES * IN_CH * sizeof(float));
    float* bufA   = (float*)carve((size_t)N_NODES * HIDDEN * sizeof(float)); // h1
    float* bufB   = (float*)carve((size_t)N_NODES * HIDDEN * sizeof(float)); // agg2/h2
    float* sums   = (float*)carve(N_GRAPHS * HIDDEN * sizeof(float));
    float* cntg   = (float*)carve(N_GRAPHS * sizeof(float));
    (void)ws_size;

    const int nodeBlocks  = (N_NODES + 255) / 256;
    const int edgeBlocks  = (N_EDGES + 255) / 256;
    const int waveNodeBlk = (N_NODES + 3) / 4;
    const int poolBlocks  = (N_NODES + POOL_CHUNK - 1) / POOL_CHUNK;

    // CSR build + normalization
    hipMemsetAsync(cnt, 0, N_NODES * sizeof(int), stream);
    hist_kernel<<<edgeBlocks, 256, 0, stream>>>(dst, cnt);
    dinv_kernel<<<nodeBlocks, 256, 0, stream>>>(cnt, dinv);
    scanA_kernel<<<N_SCAN_BLOCKS, SCAN_B, 0, stream>>>(cnt, bsum);
    scanB_kernel<<<1, SCAN_B, 0, stream>>>(bsum, boff);
    scanC_kernel<<<N_SCAN_BLOCKS, SCAN_B, 0, stream>>>(cnt, boff, rowptr);
    fill_kernel<<<edgeBlocks, 256, 0, stream>>>(src, dst, rowptr, csr);
    // rowptr now holds row-end cursors

    // layer 1: aggregate x (16 ch) then linear+relu
    agg1_kernel<<<waveNodeBlk, 256, 0, stream>>>(x, csr, rowptr, cnt, dinv, agg1);
    gemm1_relu_kernel<<<waveNodeBlk, 256, 0, stream>>>(agg1, W1, b1, bufA);

    // layer 2: aggregate h1 (64 ch) then linear+relu (in-place on bufB)
    agg2_kernel<<<waveNodeBlk, 256, 0, stream>>>(bufA, csr, rowptr, cnt, dinv, bufB);
    gemm2_relu_kernel<<<waveNodeBlk, 256, 0, stream>>>(bufB, W2, b2, bufB);

    // pool + head
    hipMemsetAsync(sums, 0, (N_GRAPHS * HIDDEN + N_GRAPHS) * sizeof(float) + 256, stream);
    pool_kernel<<<poolBlocks, 256, 0, stream>>>(bufB, bat, sums, cntg);
    head_kernel<<<1, 256, 0, stream>>>(sums, cntg, Wc, bc, out);
}

// Round 4
// 259.543 us; speedup vs baseline: 3.1040x; 1.2012x over previous
//
#include <hip/hip_runtime.h>

#define N_NODES 50000
#define N_EDGES 800000
#define N_GRAPHS 128
#define IN_CH 16
#define HIDDEN 64
#define OUT_CH 2
#define POOL_CHUNK 128
#define SCAN_B 256
#define N_SCAN_BLOCKS ((N_NODES + SCAN_B - 1) / SCAN_B)   // 196 (must be <= 256)
#define EDGE_ILP 4

// ---------------- CSR build ----------------

// One atomic-with-return per edge: rank[e] = old count of dst[e].
// 4 edges/thread, strided, so 4 atomics are in flight per lane before the wait.
__global__ void hist_rank_kernel(const int* __restrict__ dst, int* __restrict__ cnt,
                                 int* __restrict__ rank) {
    int base = blockIdx.x * (256 * EDGE_ILP) + threadIdx.x;
    int d[EDGE_ILP], r[EDGE_ILP];
#pragma unroll
    for (int k = 0; k < EDGE_ILP; k++) {
        int e = base + k * 256;
        d[k] = (e < N_EDGES) ? dst[e] : -1;
    }
#pragma unroll
    for (int k = 0; k < EDGE_ILP; k++) {
        if ((unsigned)d[k] < N_NODES) r[k] = atomicAdd(&cnt[d[k]], 1);
    }
#pragma unroll
    for (int k = 0; k < EDGE_ILP; k++) {
        int e = base + k * 256;
        if (e < N_EDGES && (unsigned)d[k] < N_NODES) rank[e] = r[k];
    }
}

// per-block sums of cnt; dinv fused (reads cnt anyway)
__global__ void scanA_kernel(const int* __restrict__ cnt, int* __restrict__ bsum,
                             float* __restrict__ dinv) {
    __shared__ int s[SCAN_B];
    int t = threadIdx.x;
    int idx = blockIdx.x * SCAN_B + t;
    int v = (idx < N_NODES) ? cnt[idx] : 0;
    if (idx < N_NODES) dinv[idx] = rsqrtf((float)(v + 1));  // +1 self-loop
    s[t] = v;
    __syncthreads();
    for (int off = SCAN_B / 2; off > 0; off >>= 1) {
        if (t < off) s[t] += s[t + off];
        __syncthreads();
    }
    if (t == 0) bsum[blockIdx.x] = s[0];
}

// exclusive scan of block sums (single block; N_SCAN_BLOCKS <= 256)
__global__ void scanB_kernel(const int* __restrict__ bsum, int* __restrict__ boff) {
    __shared__ int s[SCAN_B];
    int t = threadIdx.x;
    int v = (t < N_SCAN_BLOCKS) ? bsum[t] : 0;
    s[t] = v;
    __syncthreads();
    for (int off = 1; off < SCAN_B; off <<= 1) {
        int u = (t >= off) ? s[t - off] : 0;
        __syncthreads();
        s[t] += u;
        __syncthreads();
    }
    if (t < N_SCAN_BLOCKS) boff[t] = s[t] - v;  // exclusive
}

// rowptr[i] = exclusive prefix of cnt (NOT mutated afterwards)
__global__ void scanC_kernel(const int* __restrict__ cnt, const int* __restrict__ boff,
                             int* __restrict__ rowptr) {
    __shared__ int s[SCAN_B];
    int t = threadIdx.x;
    int idx = blockIdx.x * SCAN_B + t;
    int v = (idx < N_NODES) ? cnt[idx] : 0;
    s[t] = v;
    __syncthreads();
    for (int off = 1; off < SCAN_B; off <<= 1) {
        int u = (t >= off) ? s[t - off] : 0;
        __syncthreads();
        s[t] += u;
        __syncthreads();
    }
    if (idx < N_NODES) rowptr[idx] = boff[blockIdx.x] + s[t] - v;
}

// atomic-free fill: pos = rowptr[d] + rank[e]
__global__ void fill_kernel(const int* __restrict__ src, const int* __restrict__ dst,
                            const int* __restrict__ rank, const int* __restrict__ rowptr,
                            int* __restrict__ csr_src) {
    int base = blockIdx.x * (256 * EDGE_ILP) + threadIdx.x;
#pragma unroll
    for (int k = 0; k < EDGE_ILP; k++) {
        int e = base + k * 256;
        if (e < N_EDGES) {
            int d = dst[e];
            if ((unsigned)d < N_NODES) csr_src[rowptr[d] + rank[e]] = src[e];
        }
    }
}

// ---------------- aggregation (gather form, no atomics) ----------------

// agg1[n][0:16] = dinv[n]*sum_{s in N(n)} dinv[s]*x[s][:] + dinv[n]^2 * x[n][:]
// one wave per node; lane = c + 16*j, j in 0..3 processes every 4th edge.
__global__ void agg1_kernel(const float* __restrict__ x, const int* __restrict__ csr_src,
                            const int* __restrict__ rowptr, const int* __restrict__ cnt,
                            const float* __restrict__ dinv, float* __restrict__ agg) {
    int t = threadIdx.x;
    int n = blockIdx.x * 4 + (t >> 6);
    if (n >= N_NODES) return;
    int lane = t & 63;
    int c = lane & 15;
    int j = lane >> 4;
    int len = cnt[n];
    int start = rowptr[n];
    float acc = 0.0f;
    for (int i = j; i < len; i += 4) {
        int s = csr_src[start + i];
        acc += dinv[s] * x[s * IN_CH + c];
    }
    acc += __shfl_xor(acc, 16, 64);
    acc += __shfl_xor(acc, 32, 64);
    if (j == 0) {
        float dn = dinv[n];
        agg[n * IN_CH + c] = dn * acc + dn * dn * x[n * IN_CH + c];
    }
}

// agg[n][0:64], one wave per node, lane = channel; 4-way ILP.
__global__ void agg2_kernel(const float* __restrict__ h, const int* __restrict__ csr_src,
                            const int* __restrict__ rowptr, const int* __restrict__ cnt,
                            const float* __restrict__ dinv, float* __restrict__ agg) {
    int t = threadIdx.x;
    int n = blockIdx.x * 4 + (t >> 6);
    if (n >= N_NODES) return;
    int c = t & 63;
    int len = cnt[n];
    int start = rowptr[n];
    float acc0 = 0.0f, acc1 = 0.0f, acc2 = 0.0f, acc3 = 0.0f;
    int i = 0;
    for (; i + 3 < len; i += 4) {
        int s0 = csr_src[start + i];
        int s1 = csr_src[start + i + 1];
        int s2 = csr_src[start + i + 2];
        int s3 = csr_src[start + i + 3];
        acc0 += dinv[s0] * h[s0 * HIDDEN + c];
        acc1 += dinv[s1] * h[s1 * HIDDEN + c];
        acc2 += dinv[s2] * h[s2 * HIDDEN + c];
        acc3 += dinv[s3] * h[s3 * HIDDEN + c];
    }
    for (; i < len; i++) {
        int s0 = csr_src[start + i];
        acc0 += dinv[s0] * h[s0 * HIDDEN + c];
    }
    float dn = dinv[n];
    agg[n * HIDDEN + c] = dn * ((acc0 + acc1) + (acc2 + acc3)) + dn * dn * h[n * HIDDEN + c];
}

// ---------------- dense linear layers (bias + relu fused) ----------------

// h[n][c] = relu(sum_k a[n][k]*W[k][c] + b[c]), K=16. 16 nodes/block.
__global__ void gemm1_relu_kernel(const float* __restrict__ a, const float* __restrict__ W,
                                  const float* __restrict__ b, float* __restrict__ h) {
    __shared__ float sW[IN_CH * HIDDEN];   // 4 KB
    __shared__ float sx[16 * IN_CH];       // 1 KB
    int t = threadIdx.x;
    for (int i = t; i < IN_CH * HIDDEN; i += 256) sW[i] = W[i];
    long long base = (long long)blockIdx.x * 16 * IN_CH;
    if (t < 16 * IN_CH) {
        long long gidx = base + t;
        sx[t] = (gidx < (long long)N_NODES * IN_CH) ? a[gidx] : 0.0f;
    }
    __syncthreads();
    int r = t >> 6;
    int c = t & 63;
    float bias = b[c];
#pragma unroll
    for (int nb = 0; nb < 4; nb++) {
        int row = nb * 4 + r;
        int n = blockIdx.x * 16 + row;
        if (n >= N_NODES) continue;
        float acc = bias;
#pragma unroll
        for (int k = 0; k < IN_CH; k++) acc += sx[row * IN_CH + k] * sW[k * HIDDEN + c];
        h[n * HIDDEN + c] = acc > 0.0f ? acc : 0.0f;
    }
}

// h[n][c] = relu(sum_k a[n][k]*W[k][c] + b[c]), K=64. 16 nodes/block.
// In-place safe: block reads all 16 of its rows into LDS before writing any.
__global__ void gemm2_relu_kernel(const float* __restrict__ a, const float* __restrict__ W,
                                  const float* __restrict__ b, float* __restrict__ h) {
    __shared__ float sW[HIDDEN * HIDDEN];  // 16 KB
    __shared__ float sx[16 * HIDDEN];      // 4 KB
    int t = threadIdx.x;
    for (int i = t; i < HIDDEN * HIDDEN; i += 256) sW[i] = W[i];
    long long base = (long long)blockIdx.x * 16 * HIDDEN;
    for (int i = t; i < 16 * HIDDEN; i += 256) {
        long long gidx = base + i;
        sx[i] = (gidx < (long long)N_NODES * HIDDEN) ? a[gidx] : 0.0f;
    }
    __syncthreads();
    int r = t >> 6;
    int c = t & 63;
    float bias = b[c];
#pragma unroll
    for (int nb = 0; nb < 4; nb++) {
        int row = nb * 4 + r;
        int n = blockIdx.x * 16 + row;
        if (n >= N_NODES) continue;
        float acc = bias;
#pragma unroll
        for (int k = 0; k < HIDDEN; k++) acc += sx[row * HIDDEN + k] * sW[k * HIDDEN + c];
        h[n * HIDDEN + c] = acc > 0.0f ? acc : 0.0f;
    }
}

// ---------------- pooling + head ----------------

__global__ void pool_kernel(const float* __restrict__ act, const int* __restrict__ batch,
                            float* __restrict__ sums, float* __restrict__ cntg) {
    int t = threadIdx.x;
    int c = t & 63;
    int r = t >> 6;
    int base = blockIdx.x * POOL_CHUNK;
    int gcur = -1;
    float acc = 0.0f;
    float cacc = 0.0f;
    for (int i = r; i < POOL_CHUNK; i += 4) {
        int n = base + i;
        if (n >= N_NODES) break;
        int g = batch[n];
        if ((unsigned)g >= N_GRAPHS) continue;
        if (g != gcur) {
            if (gcur >= 0) {
                atomicAdd(&sums[gcur * HIDDEN + c], acc);
                if (c == 0) atomicAdd(&cntg[gcur], cacc);
            }
            gcur = g;
            acc = 0.0f;
            cacc = 0.0f;
        }
        acc += act[n * HIDDEN + c];
        cacc += 1.0f;
    }
    if (gcur >= 0) {
        atomicAdd(&sums[gcur * HIDDEN + c], acc);
        if (c == 0) atomicAdd(&cntg[gcur], cacc);
    }
}

__global__ void head_kernel(const float* __restrict__ sums, const float* __restrict__ cntg,
                            const float* __restrict__ Wc, const float* __restrict__ bc,
                            float* __restrict__ out) {
    int t = blockIdx.x * blockDim.x + threadIdx.x;
    if (t >= N_GRAPHS * OUT_CH) return;
    int g = t >> 1;
    int o = t & 1;
    float inv = 1.0f / fmaxf(cntg[g], 1.0f);
    float acc = bc[o];
#pragma unroll
    for (int k = 0; k < HIDDEN; k++) acc += sums[g * HIDDEN + k] * inv * Wc[k * OUT_CH + o];
    out[t] = acc;
}

// ---------------- launch ----------------

extern "C" void kernel_launch(void* const* d_in, const int* in_sizes, int n_in,
                              void* d_out, int out_size, void* d_ws, size_t ws_size,
                              hipStream_t stream) {
    const float* x  = (const float*)d_in[0];      // [N_NODES, IN_CH]
    const int* ei   = (const int*)d_in[1];        // [2, N_EDGES]
    const int* bat  = (const int*)d_in[2];        // [N_NODES]
    const float* W1 = (const float*)d_in[3];
    const float* b1 = (const float*)d_in[4];
    const float* W2 = (const float*)d_in[5];
    const float* b2 = (const float*)d_in[6];
    const float* Wc = (const float*)d_in[7];
    const float* bc = (const float*)d_in[8];
    float* out = (float*)d_out;

    const int* src = ei;
    const int* dst = ei + N_EDGES;

    char* ws = (char*)d_ws;
    size_t off = 0;
    auto carve = [&](size_t nbytes) {
        char* p = ws + off;
        off += (nbytes + 255) & ~(size_t)255;
        return p;
    };
    int*   cnt    = (int*)carve(N_NODES * sizeof(int));
    float* dinv   = (float*)carve(N_NODES * sizeof(float));
    int*   rowptr = (int*)carve(N_NODES * sizeof(int));   // exclusive prefix (immutable)
    int*   bsum   = (int*)carve(N_SCAN_BLOCKS * sizeof(int));
    int*   boff   = (int*)carve(N_SCAN_BLOCKS * sizeof(int));
    int*   rank   = (int*)carve((size_t)N_EDGES * sizeof(int));
    int*   csr    = (int*)carve((size_t)N_EDGES * sizeof(int));
    float* agg1   = (float*)carve((size_t)N_NODES * IN_CH * sizeof(float));
    float* bufA   = (float*)carve((size_t)N_NODES * HIDDEN * sizeof(float)); // h1
    float* bufB   = (float*)carve((size_t)N_NODES * HIDDEN * sizeof(float)); // agg2/h2
    float* sums   = (float*)carve(N_GRAPHS * HIDDEN * sizeof(float));
    float* cntg   = (float*)carve(N_GRAPHS * sizeof(float));
    (void)ws_size;

    const int edge4Blocks = (N_EDGES + 256 * EDGE_ILP - 1) / (256 * EDGE_ILP);
    const int waveNodeBlk = (N_NODES + 3) / 4;
    const int node16Blk   = (N_NODES + 15) / 16;
    const int poolBlocks  = (N_NODES + POOL_CHUNK - 1) / POOL_CHUNK;

    // CSR build + normalization
    hipMemsetAsync(cnt, 0, N_NODES * sizeof(int), stream);
    hist_rank_kernel<<<edge4Blocks, 256, 0, stream>>>(dst, cnt, rank);
    scanA_kernel<<<N_SCAN_BLOCKS, SCAN_B, 0, stream>>>(cnt, bsum, dinv);
    scanB_kernel<<<1, SCAN_B, 0, stream>>>(bsum, boff);
    scanC_kernel<<<N_SCAN_BLOCKS, SCAN_B, 0, stream>>>(cnt, boff, rowptr);
    fill_kernel<<<edge4Blocks, 256, 0, stream>>>(src, dst, rank, rowptr, csr);

    // layer 1: aggregate x (16 ch) then linear+relu
    agg1_kernel<<<waveNodeBlk, 256, 0, stream>>>(x, csr, rowptr, cnt, dinv, agg1);
    gemm1_relu_kernel<<<node16Blk, 256, 0, stream>>>(agg1, W1, b1, bufA);

    // layer 2: aggregate h1 (64 ch) then linear+relu (in-place on bufB)
    agg2_kernel<<<waveNodeBlk, 256, 0, stream>>>(bufA, csr, rowptr, cnt, dinv, bufB);
    gemm2_relu_kernel<<<node16Blk, 256, 0, stream>>>(bufB, W2, b2, bufB);

    // pool + head
    hipMemsetAsync(sums, 0, (N_GRAPHS * HIDDEN + N_GRAPHS) * sizeof(float) + 256, stream);
    pool_kernel<<<poolBlocks, 256, 0, stream>>>(bufB, bat, sums, cntg);
    head_kernel<<<1, 256, 0, stream>>>(sums, cntg, Wc, bc, out);
}

// Round 5
// 251.140 us; speedup vs baseline: 3.2079x; 1.0335x over previous
//
#include <hip/hip_runtime.h>
#include <hip/hip_bf16.h>

#define N_NODES 50000
#define N_EDGES 800000
#define N_GRAPHS 128
#define IN_CH 16
#define HIDDEN 64
#define OUT_CH 2
#define POOL_CHUNK 128
#define NREP 4                                  // count replicas per node
#define SCAN_ENT (N_NODES * NREP)               // 200000 scan entries
#define SCAN_CHUNK 1024                         // entries per scan block (256 thr x 4)
#define N_SCAN_BLOCKS ((SCAN_ENT + SCAN_CHUNK - 1) / SCAN_CHUNK)  // 196 (<=256)
#define EDGE_ILP 8

// ---------------- CSR build ----------------

// rank within (dst, replica): one returning atomic per edge, 8 in flight/thread,
// 4 replicas spread same-node collisions 16 -> 4.
__global__ void hist_rank_kernel(const int* __restrict__ dst, int* __restrict__ cnt2,
                                 int* __restrict__ rankp) {
    int base = blockIdx.x * (256 * EDGE_ILP) + threadIdx.x;
    int d[EDGE_ILP], r[EDGE_ILP];
#pragma unroll
    for (int k = 0; k < EDGE_ILP; k++) {
        int e = base + k * 256;
        d[k] = (e < N_EDGES) ? dst[e] : -1;
    }
#pragma unroll
    for (int k = 0; k < EDGE_ILP; k++) {
        if ((unsigned)d[k] < N_NODES) r[k] = atomicAdd(&cnt2[(d[k] << 2) | (k & 3)], 1);
    }
#pragma unroll
    for (int k = 0; k < EDGE_ILP; k++) {
        int e = base + k * 256;
        if (e < N_EDGES && (unsigned)d[k] < N_NODES) rankp[e] = (r[k] << 2) | (k & 3);
    }
}

// per-block sums over 1024 cnt2 entries; thread t owns node d = 256*blk + t
// (its 4 replicas) -> fuse cnt_node + dinv here.
__global__ void scanA_kernel(const int* __restrict__ cnt2, int* __restrict__ bsum,
                             int* __restrict__ cnt_node, float* __restrict__ dinv) {
    __shared__ int s[256];
    int t = threadIdx.x;
    int ebase = blockIdx.x * SCAN_CHUNK + t * 4;
    int v = 0;
    if (ebase + 3 < SCAN_ENT) {
        int4 c = *(const int4*)&cnt2[ebase];
        v = c.x + c.y + c.z + c.w;
    } else {
        for (int k = 0; k < 4; k++) {
            int i = ebase + k;
            if (i < SCAN_ENT) v += cnt2[i];
        }
    }
    int d = blockIdx.x * 256 + t;
    if (d < N_NODES) {
        cnt_node[d] = v;
        dinv[d] = rsqrtf((float)(v + 1));  // +1 self-loop
    }
    s[t] = v;
    __syncthreads();
    for (int off = 128; off > 0; off >>= 1) {
        if (t < off) s[t] += s[t + off];
        __syncthreads();
    }
    if (t == 0) bsum[blockIdx.x] = s[0];
}

// full exclusive scan of cnt2 -> rowptr2 (scanB folded in: each block re-scans
// the 196 block sums in LDS, 8 Hillis-Steele steps).
__global__ void scanC_kernel(const int* __restrict__ cnt2, const int* __restrict__ bsum,
                             int* __restrict__ rowptr2) {
    __shared__ int sb[256];
    __shared__ int st[256];
    int t = threadIdx.x;
    sb[t] = (t < N_SCAN_BLOCKS) ? bsum[t] : 0;
    __syncthreads();
    for (int off = 1; off < 256; off <<= 1) {
        int u = (t >= off) ? sb[t - off] : 0;
        __syncthreads();
        sb[t] += u;
        __syncthreads();
    }
    int boff = (blockIdx.x > 0) ? sb[blockIdx.x - 1] : 0;

    int ebase = blockIdx.x * SCAN_CHUNK + t * 4;
    int c0 = 0, c1 = 0, c2 = 0, c3 = 0;
    bool full = (ebase + 3 < SCAN_ENT);
    if (full) {
        int4 c = *(const int4*)&cnt2[ebase];
        c0 = c.x; c1 = c.y; c2 = c.z; c3 = c.w;
    } else {
        if (ebase < SCAN_ENT) c0 = cnt2[ebase];
        if (ebase + 1 < SCAN_ENT) c1 = cnt2[ebase + 1];
        if (ebase + 2 < SCAN_ENT) c2 = cnt2[ebase + 2];
    }
    int tsum = c0 + c1 + c2 + c3;
    st[t] = tsum;
    __syncthreads();
    for (int off = 1; off < 256; off <<= 1) {
        int u = (t >= off) ? st[t - off] : 0;
        __syncthreads();
        st[t] += u;
        __syncthreads();
    }
    int p = boff + st[t] - tsum;
    if (full) {
        int4 o;
        o.x = p; o.y = p + c0; o.z = p + c0 + c1; o.w = p + c0 + c1 + c2;
        *(int4*)&rowptr2[ebase] = o;
    } else {
        if (ebase < SCAN_ENT) rowptr2[ebase] = p;
        if (ebase + 1 < SCAN_ENT) rowptr2[ebase + 1] = p + c0;
        if (ebase + 2 < SCAN_ENT) rowptr2[ebase + 2] = p + c0 + c1;
        if (ebase + 3 < SCAN_ENT) rowptr2[ebase + 3] = p + c0 + c1 + c2;
    }
}

// atomic-free fill: pos = rowptr2[4d + rep] + rank
__global__ void fill_kernel(const int* __restrict__ src, const int* __restrict__ dst,
                            const int* __restrict__ rankp, const int* __restrict__ rowptr2,
                            int* __restrict__ csr_src) {
    int base = blockIdx.x * (256 * EDGE_ILP) + threadIdx.x;
#pragma unroll
    for (int k = 0; k < EDGE_ILP; k++) {
        int e = base + k * 256;
        if (e < N_EDGES) {
            int d = dst[e];
            if ((unsigned)d < N_NODES) {
                int rp = rankp[e];
                csr_src[rowptr2[(d << 2) | (rp & 3)] + (rp >> 2)] = src[e];
            }
        }
    }
}

// ---------------- aggregation (gather form, no atomics) ----------------

// agg1[n][0:16] = dinv[n]*sum_{s in N(n)} dinv[s]*x[s][:] + dinv[n]^2 * x[n][:]
__global__ void agg1_kernel(const float* __restrict__ x, const int* __restrict__ csr_src,
                            const int* __restrict__ rowptr2, const int* __restrict__ cnt,
                            const float* __restrict__ dinv, float* __restrict__ agg) {
    int t = threadIdx.x;
    int n = blockIdx.x * 4 + (t >> 6);
    if (n >= N_NODES) return;
    int lane = t & 63;
    int c = lane & 15;
    int j = lane >> 4;
    int len = cnt[n];
    int start = rowptr2[n << 2];
    float acc = 0.0f;
    for (int i = j; i < len; i += 4) {
        int s = csr_src[start + i];
        acc += dinv[s] * x[s * IN_CH + c];
    }
    acc += __shfl_xor(acc, 16, 64);
    acc += __shfl_xor(acc, 32, 64);
    if (j == 0) {
        float dn = dinv[n];
        agg[n * IN_CH + c] = dn * acc + dn * dn * x[n * IN_CH + c];
    }
}

// agg[n][0:64] from bf16 h (one 128B line per edge row), fp32 accumulate, 4-way ILP.
__global__ void agg2_kernel(const __hip_bfloat16* __restrict__ h, const int* __restrict__ csr_src,
                            const int* __restrict__ rowptr2, const int* __restrict__ cnt,
                            const float* __restrict__ dinv, float* __restrict__ agg) {
    int t = threadIdx.x;
    int n = blockIdx.x * 4 + (t >> 6);
    if (n >= N_NODES) return;
    int c = t & 63;
    int len = cnt[n];
    int start = rowptr2[n << 2];
    float acc0 = 0.0f, acc1 = 0.0f, acc2 = 0.0f, acc3 = 0.0f;
    int i = 0;
    for (; i + 3 < len; i += 4) {
        int s0 = csr_src[start + i];
        int s1 = csr_src[start + i + 1];
        int s2 = csr_src[start + i + 2];
        int s3 = csr_src[start + i + 3];
        acc0 += dinv[s0] * __bfloat162float(h[s0 * HIDDEN + c]);
        acc1 += dinv[s1] * __bfloat162float(h[s1 * HIDDEN + c]);
        acc2 += dinv[s2] * __bfloat162float(h[s2 * HIDDEN + c]);
        acc3 += dinv[s3] * __bfloat162float(h[s3 * HIDDEN + c]);
    }
    for (; i < len; i++) {
        int s0 = csr_src[start + i];
        acc0 += dinv[s0] * __bfloat162float(h[s0 * HIDDEN + c]);
    }
    float dn = dinv[n];
    agg[n * HIDDEN + c] =
        dn * ((acc0 + acc1) + (acc2 + acc3)) + dn * dn * __bfloat162float(h[n * HIDDEN + c]);
}

// ---------------- dense linear layers (bias + relu fused) ----------------

// h1[n][c] = relu(sum_k a[n][k]*W[k][c] + b[c]), K=16, bf16 output. 16 nodes/block.
__global__ void gemm1_relu_kernel(const float* __restrict__ a, const float* __restrict__ W,
                                  const float* __restrict__ b, __hip_bfloat16* __restrict__ h) {
    __shared__ float sW[IN_CH * HIDDEN];   // 4 KB
    __shared__ float sx[16 * IN_CH];       // 1 KB
    int t = threadIdx.x;
    for (int i = t; i < IN_CH * HIDDEN; i += 256) sW[i] = W[i];
    long long base = (long long)blockIdx.x * 16 * IN_CH;
    if (t < 16 * IN_CH) {
        long long gidx = base + t;
        sx[t] = (gidx < (long long)N_NODES * IN_CH) ? a[gidx] : 0.0f;
    }
    __syncthreads();
    int r = t >> 6;
    int c = t & 63;
    float bias = b[c];
#pragma unroll
    for (int nb = 0; nb < 4; nb++) {
        int row = nb * 4 + r;
        int n = blockIdx.x * 16 + row;
        if (n >= N_NODES) continue;
        float acc = bias;
#pragma unroll
        for (int k = 0; k < IN_CH; k++) acc += sx[row * IN_CH + k] * sW[k * HIDDEN + c];
        h[n * HIDDEN + c] = __float2bfloat16(acc > 0.0f ? acc : 0.0f);
    }
}

// h2[n][c] = relu(sum_k a[n][k]*W[k][c] + b[c]), K=64. 16 nodes/block.
// In-place safe: block stages all its rows in LDS before writing.
__global__ void gemm2_relu_kernel(const float* __restrict__ a, const float* __restrict__ W,
                                  const float* __restrict__ b, float* __restrict__ h) {
    __shared__ float sW[HIDDEN * HIDDEN];  // 16 KB
    __shared__ float sx[16 * HIDDEN];      // 4 KB
    int t = threadIdx.x;
    for (int i = t; i < HIDDEN * HIDDEN; i += 256) sW[i] = W[i];
    long long base = (long long)blockIdx.x * 16 * HIDDEN;
    for (int i = t; i < 16 * HIDDEN; i += 256) {
        long long gidx = base + i;
        sx[i] = (gidx < (long long)N_NODES * HIDDEN) ? a[gidx] : 0.0f;
    }
    __syncthreads();
    int r = t >> 6;
    int c = t & 63;
    float bias = b[c];
#pragma unroll
    for (int nb = 0; nb < 4; nb++) {
        int row = nb * 4 + r;
        int n = blockIdx.x * 16 + row;
        if (n >= N_NODES) continue;
        float acc = bias;
#pragma unroll
        for (int k = 0; k < HIDDEN; k++) acc += sx[row * HIDDEN + k] * sW[k * HIDDEN + c];
        h[n * HIDDEN + c] = acc > 0.0f ? acc : 0.0f;
    }
}

// ---------------- pooling + head ----------------

__global__ void pool_kernel(const float* __restrict__ act, const int* __restrict__ batch,
                            float* __restrict__ sums, float* __restrict__ cntg) {
    int t = threadIdx.x;
    int c = t & 63;
    int r = t >> 6;
    int base = blockIdx.x * POOL_CHUNK;
    int gcur = -1;
    float acc = 0.0f;
    float cacc = 0.0f;
    for (int i = r; i < POOL_CHUNK; i += 4) {
        int n = base + i;
        if (n >= N_NODES) break;
        int g = batch[n];
        if ((unsigned)g >= N_GRAPHS) continue;
        if (g != gcur) {
            if (gcur >= 0) {
                atomicAdd(&sums[gcur * HIDDEN + c], acc);
                if (c == 0) atomicAdd(&cntg[gcur], cacc);
            }
            gcur = g;
            acc = 0.0f;
            cacc = 0.0f;
        }
        acc += act[n * HIDDEN + c];
        cacc += 1.0f;
    }
    if (gcur >= 0) {
        atomicAdd(&sums[gcur * HIDDEN + c], acc);
        if (c == 0) atomicAdd(&cntg[gcur], cacc);
    }
}

__global__ void head_kernel(const float* __restrict__ sums, const float* __restrict__ cntg,
                            const float* __restrict__ Wc, const float* __restrict__ bc,
                            float* __restrict__ out) {
    int t = blockIdx.x * blockDim.x + threadIdx.x;
    if (t >= N_GRAPHS * OUT_CH) return;
    int g = t >> 1;
    int o = t & 1;
    float inv = 1.0f / fmaxf(cntg[g], 1.0f);
    float acc = bc[o];
#pragma unroll
    for (int k = 0; k < HIDDEN; k++) acc += sums[g * HIDDEN + k] * inv * Wc[k * OUT_CH + o];
    out[t] = acc;
}

// ---------------- launch ----------------

extern "C" void kernel_launch(void* const* d_in, const int* in_sizes, int n_in,
                              void* d_out, int out_size, void* d_ws, size_t ws_size,
                              hipStream_t stream) {
    const float* x  = (const float*)d_in[0];
    const int* ei   = (const int*)d_in[1];
    const int* bat  = (const int*)d_in[2];
    const float* W1 = (const float*)d_in[3];
    const float* b1 = (const float*)d_in[4];
    const float* W2 = (const float*)d_in[5];
    const float* b2 = (const float*)d_in[6];
    const float* Wc = (const float*)d_in[7];
    const float* bc = (const float*)d_in[8];
    float* out = (float*)d_out;

    const int* src = ei;
    const int* dst = ei + N_EDGES;

    char* ws = (char*)d_ws;
    size_t off = 0;
    auto carve = [&](size_t nbytes) {
        char* p = ws + off;
        off += (nbytes + 255) & ~(size_t)255;
        return p;
    };
    // zero-init region first (single memset): cnt2 | sums | cntg
    int*   cnt2     = (int*)carve((size_t)SCAN_ENT * sizeof(int));   // 800000 B (256-mult)
    float* sums     = (float*)carve(N_GRAPHS * HIDDEN * sizeof(float));
    float* cntg     = (float*)carve(N_GRAPHS * sizeof(float));
    size_t zeroBytes = off;
    float* dinv     = (float*)carve(N_NODES * sizeof(float));
    int*   cnt_node = (int*)carve(N_NODES * sizeof(int));
    int*   rowptr2  = (int*)carve((size_t)SCAN_ENT * sizeof(int));
    int*   bsum     = (int*)carve(N_SCAN_BLOCKS * sizeof(int));
    int*   rankp    = (int*)carve((size_t)N_EDGES * sizeof(int));
    int*   csr      = (int*)carve((size_t)N_EDGES * sizeof(int));
    float* agg1     = (float*)carve((size_t)N_NODES * IN_CH * sizeof(float));
    __hip_bfloat16* bufA = (__hip_bfloat16*)carve((size_t)N_NODES * HIDDEN * sizeof(__hip_bfloat16));
    float* bufB     = (float*)carve((size_t)N_NODES * HIDDEN * sizeof(float));
    (void)ws_size;

    const int edgeBlocks  = (N_EDGES + 256 * EDGE_ILP - 1) / (256 * EDGE_ILP);
    const int waveNodeBlk = (N_NODES + 3) / 4;
    const int node16Blk   = (N_NODES + 15) / 16;
    const int poolBlocks  = (N_NODES + POOL_CHUNK - 1) / POOL_CHUNK;

    // CSR build + normalization
    hipMemsetAsync(cnt2, 0, zeroBytes, stream);
    hist_rank_kernel<<<edgeBlocks, 256, 0, stream>>>(dst, cnt2, rankp);
    scanA_kernel<<<N_SCAN_BLOCKS, 256, 0, stream>>>(cnt2, bsum, cnt_node, dinv);
    scanC_kernel<<<N_SCAN_BLOCKS, 256, 0, stream>>>(cnt2, bsum, rowptr2);
    fill_kernel<<<edgeBlocks, 256, 0, stream>>>(src, dst, rankp, rowptr2, csr);

    // layer 1
    agg1_kernel<<<waveNodeBlk, 256, 0, stream>>>(x, csr, rowptr2, cnt_node, dinv, agg1);
    gemm1_relu_kernel<<<node16Blk, 256, 0, stream>>>(agg1, W1, b1, bufA);

    // layer 2
    agg2_kernel<<<waveNodeBlk, 256, 0, stream>>>(bufA, csr, rowptr2, cnt_node, dinv, bufB);
    gemm2_relu_kernel<<<node16Blk, 256, 0, stream>>>(bufB, W2, b2, bufB);

    // pool + head
    pool_kernel<<<poolBlocks, 256, 0, stream>>>(bufB, bat, sums, cntg);
    head_kernel<<<1, 256, 0, stream>>>(sums, cntg, Wc, bc, out);
}

// Round 6
// 229.237 us; speedup vs baseline: 3.5144x; 1.0955x over previous
//
#include <hip/hip_runtime.h>
#include <hip/hip_bf16.h>

#define N_NODES 50000
#define N_EDGES 800000
#define N_GRAPHS 128
#define IN_CH 16
#define HIDDEN 64
#define OUT_CH 2
#define POOL_CHUNK 128

// ---- bucket-sort CSR build params ----
#define BSHIFT 7
#define BNODES 128                               // nodes per bucket
#define NB ((N_NODES + BNODES - 1) / BNODES)     // 391 buckets
#define ECHUNK 4096                              // edges per S1/S3 block (256 thr x 16)
#define EB ((N_EDGES + ECHUNK - 1) / ECHUNK)     // 196 edge blocks
#define SLEN (NB * EB)                           // 76636 scan entries
#define SCHUNK 1024                              // scan entries per block (256 thr x 4)
#define NSB ((SLEN + SCHUNK - 1) / SCHUNK)       // 75 (<= 256)
#define MAXK 12                                  // bucket_csr edges/thread cap (3072/bucket; mean 2048, sd 45)

// ---------------- CSR build: LDS bucket sort (no global returning atomics) ----------------

// S1: per-block LDS histogram over buckets; write counts bucket-major bh[b*EB + blk].
__global__ void bucket_hist_kernel(const int* __restrict__ dst, int* __restrict__ bh) {
    __shared__ int lh[NB];
    int t = threadIdx.x;
    for (int i = t; i < NB; i += 256) lh[i] = 0;
    __syncthreads();
    int base = blockIdx.x * ECHUNK;
    for (int i = t; i < ECHUNK; i += 256) {
        int e = base + i;
        if (e < N_EDGES) {
            int d = dst[e];
            if ((unsigned)d < N_NODES) atomicAdd(&lh[d >> BSHIFT], 1);
        }
    }
    __syncthreads();
    for (int i = t; i < NB; i += 256) bh[i * EB + blockIdx.x] = lh[i];
}

// S2a: per-block partial sums of bh (1024 entries/block).
__global__ void scan_part_kernel(const int* __restrict__ a, int* __restrict__ bsum) {
    __shared__ int s[256];
    int t = threadIdx.x;
    int ebase = blockIdx.x * SCHUNK + t * 4;
    int v = 0;
    if (ebase + 3 < SLEN) {
        int4 c = *(const int4*)&a[ebase];
        v = c.x + c.y + c.z + c.w;
    } else {
        for (int k = 0; k < 4; k++) {
            int i = ebase + k;
            if (i < SLEN) v += a[i];
        }
    }
    s[t] = v;
    __syncthreads();
    for (int off = 128; off > 0; off >>= 1) {
        if (t < off) s[t] += s[t + off];
        __syncthreads();
    }
    if (t == 0) bsum[blockIdx.x] = s[0];
}

// S2b: full exclusive scan of bh -> boff (block-sum scan folded in; NSB <= 256).
__global__ void scan_apply_kernel(const int* __restrict__ a, const int* __restrict__ bsum,
                                  int* __restrict__ boff) {
    __shared__ int sb[256];
    __shared__ int st[256];
    int t = threadIdx.x;
    sb[t] = (t < NSB) ? bsum[t] : 0;
    __syncthreads();
    for (int off = 1; off < 256; off <<= 1) {
        int u = (t >= off) ? sb[t - off] : 0;
        __syncthreads();
        sb[t] += u;
        __syncthreads();
    }
    int blockOff = (blockIdx.x > 0) ? sb[blockIdx.x - 1] : 0;

    int ebase = blockIdx.x * SCHUNK + t * 4;
    int c0 = 0, c1 = 0, c2 = 0, c3 = 0;
    bool full = (ebase + 3 < SLEN);
    if (full) {
        int4 c = *(const int4*)&a[ebase];
        c0 = c.x; c1 = c.y; c2 = c.z; c3 = c.w;
    } else {
        if (ebase < SLEN) c0 = a[ebase];
        if (ebase + 1 < SLEN) c1 = a[ebase + 1];
        if (ebase + 2 < SLEN) c2 = a[ebase + 2];
    }
    int tsum = c0 + c1 + c2 + c3;
    st[t] = tsum;
    __syncthreads();
    for (int off = 1; off < 256; off <<= 1) {
        int u = (t >= off) ? st[t - off] : 0;
        __syncthreads();
        st[t] += u;
        __syncthreads();
    }
    int p = blockOff + st[t] - tsum;
    if (full) {
        int4 o;
        o.x = p; o.y = p + c0; o.z = p + c0 + c1; o.w = p + c0 + c1 + c2;
        *(int4*)&boff[ebase] = o;
    } else {
        if (ebase < SLEN) boff[ebase] = p;
        if (ebase + 1 < SLEN) boff[ebase + 1] = p + c0;
        if (ebase + 2 < SLEN) boff[ebase + 2] = p + c0 + c1;
        if (ebase + 3 < SLEN) boff[ebase + 3] = p + c0 + c1 + c2;
    }
}

// S3: scatter (src,dst) pairs into bucket regions; rank via LDS atomics.
__global__ void bucket_scatter_kernel(const int* __restrict__ src, const int* __restrict__ dst,
                                      const int* __restrict__ boff, int2* __restrict__ pairs) {
    __shared__ int lcnt[NB];
    __shared__ int goff[NB];
    int t = threadIdx.x;
    for (int i = t; i < NB; i += 256) {
        lcnt[i] = 0;
        goff[i] = boff[i * EB + blockIdx.x];
    }
    __syncthreads();
    int base = blockIdx.x * ECHUNK;
    for (int i = t; i < ECHUNK; i += 256) {
        int e = base + i;
        if (e < N_EDGES) {
            int d = dst[e];
            if ((unsigned)d < N_NODES) {
                int b = d >> BSHIFT;
                int r = atomicAdd(&lcnt[b], 1);
                int2 p;
                p.x = src[e];
                p.y = d;
                pairs[goff[b] + r] = p;
            }
        }
    }
}

// S4: one block per bucket -> exact per-node CSR; rowptr/cnt/dinv fused.
__global__ void bucket_csr_kernel(const int2* __restrict__ pairs, const int* __restrict__ boff,
                                  int* __restrict__ csr, int* __restrict__ rowptr,
                                  int* __restrict__ cnt_node, float* __restrict__ dinv) {
    __shared__ int lcnt[BNODES];
    __shared__ int ls[BNODES];
    __shared__ int lrow[BNODES];
    int b = blockIdx.x;
    int t = threadIdx.x;
    if (t < BNODES) lcnt[t] = 0;
    __syncthreads();
    int bstart = boff[b * EB];
    int bend = (b + 1 < NB) ? boff[(b + 1) * EB] : N_EDGES;
    int K = bend - bstart;
    int myn[MAXK], myr[MAXK], mys[MAXK];
#pragma unroll
    for (int k = 0; k < MAXK; k++) {
        int i = k * 256 + t;
        if (i < K) {
            int2 p = pairs[bstart + i];
            int nl = p.y & (BNODES - 1);
            mys[k] = p.x;
            myn[k] = nl;
            myr[k] = atomicAdd(&lcnt[nl], 1);
        }
    }
    __syncthreads();
    if (t < BNODES) ls[t] = lcnt[t];
    __syncthreads();
    for (int off = 1; off < BNODES; off <<= 1) {
        int u = (t >= off && t < BNODES) ? ls[t - off] : 0;
        __syncthreads();
        if (t < BNODES) ls[t] += u;
        __syncthreads();
    }
    if (t < BNODES) {
        int ex = ls[t] - lcnt[t];   // exclusive prefix within bucket
        lrow[t] = ex;
        int n = b * BNODES + t;
        if (n < N_NODES) {
            rowptr[n] = bstart + ex;
            cnt_node[n] = lcnt[t];
            dinv[n] = rsqrtf((float)(lcnt[t] + 1));  // +1 self-loop
        }
    }
    __syncthreads();
#pragma unroll
    for (int k = 0; k < MAXK; k++) {
        int i = k * 256 + t;
        if (i < K) csr[bstart + lrow[myn[k]] + myr[k]] = mys[k];
    }
}

// ---------------- aggregation (gather form, no atomics) ----------------

// agg1[n][0:16] = dinv[n]*sum_{s in N(n)} dinv[s]*x[s][:] + dinv[n]^2 * x[n][:]
__global__ void agg1_kernel(const float* __restrict__ x, const int* __restrict__ csr_src,
                            const int* __restrict__ rowptr, const int* __restrict__ cnt,
                            const float* __restrict__ dinv, float* __restrict__ agg) {
    int t = threadIdx.x;
    int n = blockIdx.x * 4 + (t >> 6);
    if (n >= N_NODES) return;
    int lane = t & 63;
    int c = lane & 15;
    int j = lane >> 4;
    int len = cnt[n];
    int start = rowptr[n];
    float acc = 0.0f;
    for (int i = j; i < len; i += 4) {
        int s = csr_src[start + i];
        acc += dinv[s] * x[s * IN_CH + c];
    }
    acc += __shfl_xor(acc, 16, 64);
    acc += __shfl_xor(acc, 32, 64);
    if (j == 0) {
        float dn = dinv[n];
        agg[n * IN_CH + c] = dn * acc + dn * dn * x[n * IN_CH + c];
    }
}

// agg[n][0:64] from bf16 h (one 128B line per edge row), fp32 accumulate, 4-way ILP.
__global__ void agg2_kernel(const __hip_bfloat16* __restrict__ h, const int* __restrict__ csr_src,
                            const int* __restrict__ rowptr, const int* __restrict__ cnt,
                            const float* __restrict__ dinv, float* __restrict__ agg) {
    int t = threadIdx.x;
    int n = blockIdx.x * 4 + (t >> 6);
    if (n >= N_NODES) return;
    int c = t & 63;
    int len = cnt[n];
    int start = rowptr[n];
    float acc0 = 0.0f, acc1 = 0.0f, acc2 = 0.0f, acc3 = 0.0f;
    int i = 0;
    for (; i + 3 < len; i += 4) {
        int s0 = csr_src[start + i];
        int s1 = csr_src[start + i + 1];
        int s2 = csr_src[start + i + 2];
        int s3 = csr_src[start + i + 3];
        acc0 += dinv[s0] * __bfloat162float(h[s0 * HIDDEN + c]);
        acc1 += dinv[s1] * __bfloat162float(h[s1 * HIDDEN + c]);
        acc2 += dinv[s2] * __bfloat162float(h[s2 * HIDDEN + c]);
        acc3 += dinv[s3] * __bfloat162float(h[s3 * HIDDEN + c]);
    }
    for (; i < len; i++) {
        int s0 = csr_src[start + i];
        acc0 += dinv[s0] * __bfloat162float(h[s0 * HIDDEN + c]);
    }
    float dn = dinv[n];
    agg[n * HIDDEN + c] =
        dn * ((acc0 + acc1) + (acc2 + acc3)) + dn * dn * __bfloat162float(h[n * HIDDEN + c]);
}

// ---------------- dense linear layers (bias + relu fused) ----------------

__global__ void gemm1_relu_kernel(const float* __restrict__ a, const float* __restrict__ W,
                                  const float* __restrict__ b, __hip_bfloat16* __restrict__ h) {
    __shared__ float sW[IN_CH * HIDDEN];   // 4 KB
    __shared__ float sx[16 * IN_CH];       // 1 KB
    int t = threadIdx.x;
    for (int i = t; i < IN_CH * HIDDEN; i += 256) sW[i] = W[i];
    long long base = (long long)blockIdx.x * 16 * IN_CH;
    if (t < 16 * IN_CH) {
        long long gidx = base + t;
        sx[t] = (gidx < (long long)N_NODES * IN_CH) ? a[gidx] : 0.0f;
    }
    __syncthreads();
    int r = t >> 6;
    int c = t & 63;
    float bias = b[c];
#pragma unroll
    for (int nb = 0; nb < 4; nb++) {
        int row = nb * 4 + r;
        int n = blockIdx.x * 16 + row;
        if (n >= N_NODES) continue;
        float acc = bias;
#pragma unroll
        for (int k = 0; k < IN_CH; k++) acc += sx[row * IN_CH + k] * sW[k * HIDDEN + c];
        h[n * HIDDEN + c] = __float2bfloat16(acc > 0.0f ? acc : 0.0f);
    }
}

__global__ void gemm2_relu_kernel(const float* __restrict__ a, const float* __restrict__ W,
                                  const float* __restrict__ b, float* __restrict__ h) {
    __shared__ float sW[HIDDEN * HIDDEN];  // 16 KB
    __shared__ float sx[16 * HIDDEN];      // 4 KB
    int t = threadIdx.x;
    for (int i = t; i < HIDDEN * HIDDEN; i += 256) sW[i] = W[i];
    long long base = (long long)blockIdx.x * 16 * HIDDEN;
    for (int i = t; i < 16 * HIDDEN; i += 256) {
        long long gidx = base + i;
        sx[i] = (gidx < (long long)N_NODES * HIDDEN) ? a[gidx] : 0.0f;
    }
    __syncthreads();
    int r = t >> 6;
    int c = t & 63;
    float bias = b[c];
#pragma unroll
    for (int nb = 0; nb < 4; nb++) {
        int row = nb * 4 + r;
        int n = blockIdx.x * 16 + row;
        if (n >= N_NODES) continue;
        float acc = bias;
#pragma unroll
        for (int k = 0; k < HIDDEN; k++) acc += sx[row * HIDDEN + k] * sW[k * HIDDEN + c];
        h[n * HIDDEN + c] = acc > 0.0f ? acc : 0.0f;
    }
}

// ---------------- pooling + head ----------------

__global__ void pool_kernel(const float* __restrict__ act, const int* __restrict__ batch,
                            float* __restrict__ sums, float* __restrict__ cntg) {
    int t = threadIdx.x;
    int c = t & 63;
    int r = t >> 6;
    int base = blockIdx.x * POOL_CHUNK;
    int gcur = -1;
    float acc = 0.0f;
    float cacc = 0.0f;
    for (int i = r; i < POOL_CHUNK; i += 4) {
        int n = base + i;
        if (n >= N_NODES) break;
        int g = batch[n];
        if ((unsigned)g >= N_GRAPHS) continue;
        if (g != gcur) {
            if (gcur >= 0) {
                atomicAdd(&sums[gcur * HIDDEN + c], acc);
                if (c == 0) atomicAdd(&cntg[gcur], cacc);
            }
            gcur = g;
            acc = 0.0f;
            cacc = 0.0f;
        }
        acc += act[n * HIDDEN + c];
        cacc += 1.0f;
    }
    if (gcur >= 0) {
        atomicAdd(&sums[gcur * HIDDEN + c], acc);
        if (c == 0) atomicAdd(&cntg[gcur], cacc);
    }
}

__global__ void head_kernel(const float* __restrict__ sums, const float* __restrict__ cntg,
                            const float* __restrict__ Wc, const float* __restrict__ bc,
                            float* __restrict__ out) {
    int t = blockIdx.x * blockDim.x + threadIdx.x;
    if (t >= N_GRAPHS * OUT_CH) return;
    int g = t >> 1;
    int o = t & 1;
    float inv = 1.0f / fmaxf(cntg[g], 1.0f);
    float acc = bc[o];
#pragma unroll
    for (int k = 0; k < HIDDEN; k++) acc += sums[g * HIDDEN + k] * inv * Wc[k * OUT_CH + o];
    out[t] = acc;
}

// ---------------- launch ----------------

extern "C" void kernel_launch(void* const* d_in, const int* in_sizes, int n_in,
                              void* d_out, int out_size, void* d_ws, size_t ws_size,
                              hipStream_t stream) {
    const float* x  = (const float*)d_in[0];
    const int* ei   = (const int*)d_in[1];
    const int* bat  = (const int*)d_in[2];
    const float* W1 = (const float*)d_in[3];
    const float* b1 = (const float*)d_in[4];
    const float* W2 = (const float*)d_in[5];
    const float* b2 = (const float*)d_in[6];
    const float* Wc = (const float*)d_in[7];
    const float* bc = (const float*)d_in[8];
    float* out = (float*)d_out;

    const int* src = ei;
    const int* dst = ei + N_EDGES;

    char* ws = (char*)d_ws;
    size_t off = 0;
    auto carve = [&](size_t nbytes) {
        char* p = ws + off;
        off += (nbytes + 255) & ~(size_t)255;
        return p;
    };
    // zero-init region first (single small memset): sums | cntg
    float* sums     = (float*)carve(N_GRAPHS * HIDDEN * sizeof(float));
    float* cntg     = (float*)carve(N_GRAPHS * sizeof(float));
    size_t zeroBytes = off;
    int*   bh       = (int*)carve((size_t)SLEN * sizeof(int));
    int*   bsum     = (int*)carve(NSB * sizeof(int));
    int*   boff     = (int*)carve((size_t)SLEN * sizeof(int));
    int2*  pairs    = (int2*)carve((size_t)N_EDGES * sizeof(int2));
    int*   csr      = (int*)carve((size_t)N_EDGES * sizeof(int));
    int*   rowptr   = (int*)carve(N_NODES * sizeof(int));
    int*   cnt_node = (int*)carve(N_NODES * sizeof(int));
    float* dinv     = (float*)carve(N_NODES * sizeof(float));
    float* agg1     = (float*)carve((size_t)N_NODES * IN_CH * sizeof(float));
    __hip_bfloat16* bufA = (__hip_bfloat16*)carve((size_t)N_NODES * HIDDEN * sizeof(__hip_bfloat16));
    float* bufB     = (float*)carve((size_t)N_NODES * HIDDEN * sizeof(float));
    (void)ws_size;

    const int waveNodeBlk = (N_NODES + 3) / 4;
    const int node16Blk   = (N_NODES + 15) / 16;
    const int poolBlocks  = (N_NODES + POOL_CHUNK - 1) / POOL_CHUNK;

    // CSR build via LDS bucket sort (no global returning atomics)
    hipMemsetAsync(sums, 0, zeroBytes, stream);
    bucket_hist_kernel<<<EB, 256, 0, stream>>>(dst, bh);
    scan_part_kernel<<<NSB, 256, 0, stream>>>(bh, bsum);
    scan_apply_kernel<<<NSB, 256, 0, stream>>>(bh, bsum, boff);
    bucket_scatter_kernel<<<EB, 256, 0, stream>>>(src, dst, boff, pairs);
    bucket_csr_kernel<<<NB, 256, 0, stream>>>(pairs, boff, csr, rowptr, cnt_node, dinv);

    // layer 1
    agg1_kernel<<<waveNodeBlk, 256, 0, stream>>>(x, csr, rowptr, cnt_node, dinv, agg1);
    gemm1_relu_kernel<<<node16Blk, 256, 0, stream>>>(agg1, W1, b1, bufA);

    // layer 2
    agg2_kernel<<<waveNodeBlk, 256, 0, stream>>>(bufA, csr, rowptr, cnt_node, dinv, bufB);
    gemm2_relu_kernel<<<node16Blk, 256, 0, stream>>>(bufB, W2, b2, bufB);

    // pool + head
    pool_kernel<<<poolBlocks, 256, 0, stream>>>(bufB, bat, sums, cntg);
    head_kernel<<<1, 256, 0, stream>>>(sums, cntg, Wc, bc, out);
}

// Round 7
// 205.016 us; speedup vs baseline: 3.9296x; 1.1181x over previous
//
#include <hip/hip_runtime.h>
#include <hip/hip_bf16.h>

#define N_NODES 50000
#define N_EDGES 800000
#define N_GRAPHS 128
#define IN_CH 16
#define HIDDEN 64
#define OUT_CH 2

// ---- bucket-sort CSR build params ----
#define BSHIFT 7
#define BNODES 128                               // nodes per bucket
#define NB ((N_NODES + BNODES - 1) / BNODES)     // 391 buckets
#define ECHUNK 4096                              // edges per S1/S3 block (256 thr x 16)
#define EB ((N_EDGES + ECHUNK - 1) / ECHUNK)     // 196 edge blocks
#define SLEN (NB * EB)                           // 76636 scan entries
#define SCHUNK 1024                              // scan entries per block (256 thr x 4)
#define NSB ((SLEN + SCHUNK - 1) / SCHUNK)       // 75 (<= 256)
#define MAXK 12                                  // bucket_csr edges/thread cap (3072/bucket; mean 2048, sd 45)

// ---------------- CSR build: LDS bucket sort (no global returning atomics) ----------------

// S1: per-block LDS histogram over buckets; counts bucket-major bh[b*EB + blk].
// Block 0 also zeroes sums|cntg (used only by fused_l2, 4 kernels later).
__global__ void bucket_hist_kernel(const int* __restrict__ dst, int* __restrict__ bh,
                                   float* __restrict__ sums, float* __restrict__ cntg) {
    __shared__ int lh[NB];
    int t = threadIdx.x;
    if (blockIdx.x == 0) {
        for (int i = t; i < N_GRAPHS * HIDDEN; i += 256) sums[i] = 0.0f;
        if (t < N_GRAPHS) cntg[t] = 0.0f;
    }
    for (int i = t; i < NB; i += 256) lh[i] = 0;
    __syncthreads();
    int base = blockIdx.x * ECHUNK;
    for (int i = t; i < ECHUNK; i += 256) {
        int e = base + i;
        if (e < N_EDGES) {
            int d = dst[e];
            if ((unsigned)d < N_NODES) atomicAdd(&lh[d >> BSHIFT], 1);
        }
    }
    __syncthreads();
    for (int i = t; i < NB; i += 256) bh[i * EB + blockIdx.x] = lh[i];
}

// S2a: per-block partial sums of bh (1024 entries/block).
__global__ void scan_part_kernel(const int* __restrict__ a, int* __restrict__ bsum) {
    __shared__ int s[256];
    int t = threadIdx.x;
    int ebase = blockIdx.x * SCHUNK + t * 4;
    int v = 0;
    if (ebase + 3 < SLEN) {
        int4 c = *(const int4*)&a[ebase];
        v = c.x + c.y + c.z + c.w;
    } else {
        for (int k = 0; k < 4; k++) {
            int i = ebase + k;
            if (i < SLEN) v += a[i];
        }
    }
    s[t] = v;
    __syncthreads();
    for (int off = 128; off > 0; off >>= 1) {
        if (t < off) s[t] += s[t + off];
        __syncthreads();
    }
    if (t == 0) bsum[blockIdx.x] = s[0];
}

// S2b: full exclusive scan of bh -> boff (block-sum scan folded in; NSB <= 256).
__global__ void scan_apply_kernel(const int* __restrict__ a, const int* __restrict__ bsum,
                                  int* __restrict__ boff) {
    __shared__ int sb[256];
    __shared__ int st[256];
    int t = threadIdx.x;
    sb[t] = (t < NSB) ? bsum[t] : 0;
    __syncthreads();
    for (int off = 1; off < 256; off <<= 1) {
        int u = (t >= off) ? sb[t - off] : 0;
        __syncthreads();
        sb[t] += u;
        __syncthreads();
    }
    int blockOff = (blockIdx.x > 0) ? sb[blockIdx.x - 1] : 0;

    int ebase = blockIdx.x * SCHUNK + t * 4;
    int c0 = 0, c1 = 0, c2 = 0, c3 = 0;
    bool full = (ebase + 3 < SLEN);
    if (full) {
        int4 c = *(const int4*)&a[ebase];
        c0 = c.x; c1 = c.y; c2 = c.z; c3 = c.w;
    } else {
        if (ebase < SLEN) c0 = a[ebase];
        if (ebase + 1 < SLEN) c1 = a[ebase + 1];
        if (ebase + 2 < SLEN) c2 = a[ebase + 2];
    }
    int tsum = c0 + c1 + c2 + c3;
    st[t] = tsum;
    __syncthreads();
    for (int off = 1; off < 256; off <<= 1) {
        int u = (t >= off) ? st[t - off] : 0;
        __syncthreads();
        st[t] += u;
        __syncthreads();
    }
    int p = blockOff + st[t] - tsum;
    if (full) {
        int4 o;
        o.x = p; o.y = p + c0; o.z = p + c0 + c1; o.w = p + c0 + c1 + c2;
        *(int4*)&boff[ebase] = o;
    } else {
        if (ebase < SLEN) boff[ebase] = p;
        if (ebase + 1 < SLEN) boff[ebase + 1] = p + c0;
        if (ebase + 2 < SLEN) boff[ebase + 2] = p + c0 + c1;
        if (ebase + 3 < SLEN) boff[ebase + 3] = p + c0 + c1 + c2;
    }
}

// S3: scatter (src,dst) pairs into bucket regions; rank via LDS atomics.
__global__ void bucket_scatter_kernel(const int* __restrict__ src, const int* __restrict__ dst,
                                      const int* __restrict__ boff, int2* __restrict__ pairs) {
    __shared__ int lcnt[NB];
    __shared__ int goff[NB];
    int t = threadIdx.x;
    for (int i = t; i < NB; i += 256) {
        lcnt[i] = 0;
        goff[i] = boff[i * EB + blockIdx.x];
    }
    __syncthreads();
    int base = blockIdx.x * ECHUNK;
    for (int i = t; i < ECHUNK; i += 256) {
        int e = base + i;
        if (e < N_EDGES) {
            int d = dst[e];
            if ((unsigned)d < N_NODES) {
                int b = d >> BSHIFT;
                int r = atomicAdd(&lcnt[b], 1);
                int2 p;
                p.x = src[e];
                p.y = d;
                pairs[goff[b] + r] = p;
            }
        }
    }
}

// S4: one block per bucket -> exact per-node CSR; rowptr/cnt/dinv fused.
__global__ void bucket_csr_kernel(const int2* __restrict__ pairs, const int* __restrict__ boff,
                                  int* __restrict__ csr, int* __restrict__ rowptr,
                                  int* __restrict__ cnt_node, float* __restrict__ dinv) {
    __shared__ int lcnt[BNODES];
    __shared__ int ls[BNODES];
    __shared__ int lrow[BNODES];
    int b = blockIdx.x;
    int t = threadIdx.x;
    if (t < BNODES) lcnt[t] = 0;
    __syncthreads();
    int bstart = boff[b * EB];
    int bend = (b + 1 < NB) ? boff[(b + 1) * EB] : N_EDGES;
    int K = bend - bstart;
    int myn[MAXK], myr[MAXK], mys[MAXK];
#pragma unroll
    for (int k = 0; k < MAXK; k++) {
        int i = k * 256 + t;
        if (i < K) {
            int2 p = pairs[bstart + i];
            int nl = p.y & (BNODES - 1);
            mys[k] = p.x;
            myn[k] = nl;
            myr[k] = atomicAdd(&lcnt[nl], 1);
        }
    }
    __syncthreads();
    if (t < BNODES) ls[t] = lcnt[t];
    __syncthreads();
    for (int off = 1; off < BNODES; off <<= 1) {
        int u = (t >= off && t < BNODES) ? ls[t - off] : 0;
        __syncthreads();
        if (t < BNODES) ls[t] += u;
        __syncthreads();
    }
    if (t < BNODES) {
        int ex = ls[t] - lcnt[t];   // exclusive prefix within bucket
        lrow[t] = ex;
        int n = b * BNODES + t;
        if (n < N_NODES) {
            rowptr[n] = bstart + ex;
            cnt_node[n] = lcnt[t];
            dinv[n] = rsqrtf((float)(lcnt[t] + 1));  // +1 self-loop
        }
    }
    __syncthreads();
#pragma unroll
    for (int k = 0; k < MAXK; k++) {
        int i = k * 256 + t;
        if (i < K) csr[bstart + lrow[myn[k]] + myr[k]] = mys[k];
    }
}

// ---------------- fused layer 1: aggregate(x) -> LDS -> linear+relu -> h1 (bf16) ----------------

// 16 nodes/block. Phase A: wave w aggregates nodes 4w..4w+3 (lane: c=l&15, j=l>>4,
// 4-way edge ILP, shuffle-reduce). Phase B: gemm1 from LDS. One barrier.
__global__ void fused_l1_kernel(const float* __restrict__ x, const int* __restrict__ csr_src,
                                const int* __restrict__ rowptr, const int* __restrict__ cnt,
                                const float* __restrict__ dinv, const float* __restrict__ W,
                                const float* __restrict__ b, __hip_bfloat16* __restrict__ h) {
    __shared__ float sW[IN_CH * HIDDEN];   // 4 KB
    __shared__ float sx[16 * IN_CH];       // 1 KB
    int t = threadIdx.x;
    for (int i = t; i < IN_CH * HIDDEN; i += 256) sW[i] = W[i];

    int n0 = blockIdx.x * 16;
    int w = t >> 6;
    int lane = t & 63;
    int c16 = lane & 15;
    int j = lane >> 4;
    for (int q = 0; q < 4; q++) {
        int row = w * 4 + q;
        int n = n0 + row;
        if (n >= N_NODES) break;
        int len = cnt[n];
        int start = rowptr[n];
        float acc = 0.0f;
        for (int i = j; i < len; i += 4) {
            int s = csr_src[start + i];
            acc += dinv[s] * x[s * IN_CH + c16];
        }
        acc += __shfl_xor(acc, 16, 64);
        acc += __shfl_xor(acc, 32, 64);
        if (j == 0) {
            float dn = dinv[n];
            sx[row * IN_CH + c16] = dn * acc + dn * dn * x[n * IN_CH + c16];
        }
    }
    __syncthreads();

    int r = t >> 6;
    int c = t & 63;
    float bias = b[c];
#pragma unroll
    for (int nb = 0; nb < 4; nb++) {
        int row = nb * 4 + r;
        int n = n0 + row;
        if (n >= N_NODES) continue;
        float acc = bias;
#pragma unroll
        for (int k = 0; k < IN_CH; k++) acc += sx[row * IN_CH + k] * sW[k * HIDDEN + c];
        h[n * HIDDEN + c] = __float2bfloat16(acc > 0.0f ? acc : 0.0f);
    }
}

// ---------------- fused layer 2: aggregate(h1) -> LDS -> linear+relu -> pool ----------------

// 16 nodes/block. h2 never touches global memory.
__global__ void fused_l2_kernel(const __hip_bfloat16* __restrict__ h, const int* __restrict__ csr_src,
                                const int* __restrict__ rowptr, const int* __restrict__ cnt,
                                const float* __restrict__ dinv, const float* __restrict__ W,
                                const float* __restrict__ b, const int* __restrict__ batch,
                                float* __restrict__ sums, float* __restrict__ cntg) {
    __shared__ float sW[HIDDEN * HIDDEN];  // 16 KB
    __shared__ float sagg[16 * HIDDEN];    // 4 KB: agg rows, then h2 rows
    __shared__ float sred[4 * HIDDEN];     // 1 KB: pool fast-path reduce
    int t = threadIdx.x;
    for (int i = t; i < HIDDEN * HIDDEN; i += 256) sW[i] = W[i];

    int n0 = blockIdx.x * 16;
    int w = t >> 6;
    int c = t & 63;

    // Phase A: wave w aggregates nodes 4w..4w+3 (lane = channel, 4-way edge ILP)
    for (int q = 0; q < 4; q++) {
        int row = w * 4 + q;
        int n = n0 + row;
        if (n >= N_NODES) break;
        int len = cnt[n];
        int start = rowptr[n];
        float acc0 = 0.0f, acc1 = 0.0f, acc2 = 0.0f, acc3 = 0.0f;
        int i = 0;
        for (; i + 3 < len; i += 4) {
            int s0 = csr_src[start + i];
            int s1 = csr_src[start + i + 1];
            int s2 = csr_src[start + i + 2];
            int s3 = csr_src[start + i + 3];
            acc0 += dinv[s0] * __bfloat162float(h[s0 * HIDDEN + c]);
            acc1 += dinv[s1] * __bfloat162float(h[s1 * HIDDEN + c]);
            acc2 += dinv[s2] * __bfloat162float(h[s2 * HIDDEN + c]);
            acc3 += dinv[s3] * __bfloat162float(h[s3 * HIDDEN + c]);
        }
        for (; i < len; i++) {
            int s0 = csr_src[start + i];
            acc0 += dinv[s0] * __bfloat162float(h[s0 * HIDDEN + c]);
        }
        float dn = dinv[n];
        sagg[row * HIDDEN + c] =
            dn * ((acc0 + acc1) + (acc2 + acc3)) + dn * dn * __bfloat162float(h[n * HIDDEN + c]);
    }
    __syncthreads();

    // Phase B: gemm2 + bias + relu (outputs in registers)
    int r = w;
    float bias = b[c];
    float vout[4];
#pragma unroll
    for (int nb = 0; nb < 4; nb++) {
        int row = nb * 4 + r;
        int n = n0 + row;
        vout[nb] = 0.0f;
        if (n >= N_NODES) continue;
        float acc = bias;
#pragma unroll
        for (int k = 0; k < HIDDEN; k++) acc += sagg[row * HIDDEN + k] * sW[k * HIDDEN + c];
        vout[nb] = acc > 0.0f ? acc : 0.0f;
    }
    __syncthreads();  // all sagg reads done

    // write h2 rows into sagg
#pragma unroll
    for (int nb = 0; nb < 4; nb++) {
        int row = nb * 4 + r;
        if (n0 + row < N_NODES) sagg[row * HIDDEN + c] = vout[nb];
    }
    __syncthreads();

    // Phase C: pool. batch is sorted -> usually whole tile is one graph.
    int nlast = n0 + 15;
    if (nlast >= N_NODES) nlast = N_NODES - 1;
    int glo = batch[n0];
    int ghi = batch[nlast];
    if (glo == ghi) {
        float p = 0.0f;
#pragma unroll
        for (int q = 0; q < 4; q++) {
            int row = 4 * r + q;
            if (n0 + row < N_NODES) p += sagg[row * HIDDEN + c];
        }
        sred[r * HIDDEN + c] = p;
        __syncthreads();
        if (r == 0) {
            float v = sred[c] + sred[HIDDEN + c] + sred[2 * HIDDEN + c] + sred[3 * HIDDEN + c];
            atomicAdd(&sums[glo * HIDDEN + c], v);
            if (c == 0) atomicAdd(&cntg[glo], (float)(nlast - n0 + 1));
        }
    } else {
        int gcur = -1;
        float acc = 0.0f, cc = 0.0f;
        for (int q = 0; q < 4; q++) {
            int row = 4 * r + q;
            int n = n0 + row;
            if (n >= N_NODES) break;
            int g = batch[n];
            if ((unsigned)g >= N_GRAPHS) continue;
            if (g != gcur) {
                if (gcur >= 0) {
                    atomicAdd(&sums[gcur * HIDDEN + c], acc);
                    if (c == 0) atomicAdd(&cntg[gcur], cc);
                }
                gcur = g;
                acc = 0.0f;
                cc = 0.0f;
            }
            acc += sagg[row * HIDDEN + c];
            cc += 1.0f;
        }
        if (gcur >= 0) {
            atomicAdd(&sums[gcur * HIDDEN + c], acc);
            if (c == 0) atomicAdd(&cntg[gcur], cc);
        }
    }
}

// ---------------- head ----------------

__global__ void head_kernel(const float* __restrict__ sums, const float* __restrict__ cntg,
                            const float* __restrict__ Wc, const float* __restrict__ bc,
                            float* __restrict__ out) {
    int t = blockIdx.x * blockDim.x + threadIdx.x;
    if (t >= N_GRAPHS * OUT_CH) return;
    int g = t >> 1;
    int o = t & 1;
    float inv = 1.0f / fmaxf(cntg[g], 1.0f);
    float acc = bc[o];
#pragma unroll
    for (int k = 0; k < HIDDEN; k++) acc += sums[g * HIDDEN + k] * inv * Wc[k * OUT_CH + o];
    out[t] = acc;
}

// ---------------- launch ----------------

extern "C" void kernel_launch(void* const* d_in, const int* in_sizes, int n_in,
                              void* d_out, int out_size, void* d_ws, size_t ws_size,
                              hipStream_t stream) {
    const float* x  = (const float*)d_in[0];
    const int* ei   = (const int*)d_in[1];
    const int* bat  = (const int*)d_in[2];
    const float* W1 = (const float*)d_in[3];
    const float* b1 = (const float*)d_in[4];
    const float* W2 = (const float*)d_in[5];
    const float* b2 = (const float*)d_in[6];
    const float* Wc = (const float*)d_in[7];
    const float* bc = (const float*)d_in[8];
    float* out = (float*)d_out;

    const int* src = ei;
    const int* dst = ei + N_EDGES;

    char* ws = (char*)d_ws;
    size_t off = 0;
    auto carve = [&](size_t nbytes) {
        char* p = ws + off;
        off += (nbytes + 255) & ~(size_t)255;
        return p;
    };
    float* sums     = (float*)carve(N_GRAPHS * HIDDEN * sizeof(float));
    float* cntg     = (float*)carve(N_GRAPHS * sizeof(float));
    int*   bh       = (int*)carve((size_t)SLEN * sizeof(int));
    int*   bsum     = (int*)carve(NSB * sizeof(int));
    int*   boff     = (int*)carve((size_t)SLEN * sizeof(int));
    int2*  pairs    = (int2*)carve((size_t)N_EDGES * sizeof(int2));
    int*   csr      = (int*)carve((size_t)N_EDGES * sizeof(int));
    int*   rowptr   = (int*)carve(N_NODES * sizeof(int));
    int*   cnt_node = (int*)carve(N_NODES * sizeof(int));
    float* dinv     = (float*)carve(N_NODES * sizeof(float));
    __hip_bfloat16* bufA = (__hip_bfloat16*)carve((size_t)N_NODES * HIDDEN * sizeof(__hip_bfloat16));
    (void)ws_size;

    const int node16Blk = (N_NODES + 15) / 16;

    // CSR build via LDS bucket sort (no global returning atomics, no memset)
    bucket_hist_kernel<<<EB, 256, 0, stream>>>(dst, bh, sums, cntg);
    scan_part_kernel<<<NSB, 256, 0, stream>>>(bh, bsum);
    scan_apply_kernel<<<NSB, 256, 0, stream>>>(bh, bsum, boff);
    bucket_scatter_kernel<<<EB, 256, 0, stream>>>(src, dst, boff, pairs);
    bucket_csr_kernel<<<NB, 256, 0, stream>>>(pairs, boff, csr, rowptr, cnt_node, dinv);

    // fused layers
    fused_l1_kernel<<<node16Blk, 256, 0, stream>>>(x, csr, rowptr, cnt_node, dinv, W1, b1, bufA);
    fused_l2_kernel<<<node16Blk, 256, 0, stream>>>(bufA, csr, rowptr, cnt_node, dinv, W2, b2,
                                                   bat, sums, cntg);
    head_kernel<<<1, 256, 0, stream>>>(sums, cntg, Wc, bc, out);
}

// Round 8
// 183.441 us; speedup vs baseline: 4.3917x; 1.1176x over previous
//
#include <hip/hip_runtime.h>
#include <hip/hip_bf16.h>

#define N_NODES 50000
#define N_EDGES 800000
#define N_GRAPHS 128
#define IN_CH 16
#define HIDDEN 64
#define OUT_CH 2

// ---- bucket-sort CSR build params ----
#define BSHIFT 7
#define BNODES 128                               // nodes per bucket
#define NB ((N_NODES + BNODES - 1) / BNODES)     // 391 buckets
#define ECHUNK 4096                              // edges per S1/S3 block (256 thr x 16)
#define EB ((N_EDGES + ECHUNK - 1) / ECHUNK)     // 196 edge blocks
#define SLEN (NB * EB)                           // 76636 scan entries
#define SCHUNK 1024                              // scan entries per block (256 thr x 4)
#define NSB ((SLEN + SCHUNK - 1) / SCHUNK)       // 75 (<= 256)
#define MAXK 12                                  // bucket_csr edges/thread cap (3072/bucket)
#define WT_LD 68                                 // transposed-W LDS stride (16B-aligned, banks spread)

__device__ __forceinline__ float bf2f(unsigned short u) {
    return __uint_as_float(((unsigned)u) << 16);
}

// ---------------- CSR build: LDS bucket sort (no global returning atomics) ----------------

__global__ void bucket_hist_kernel(const int* __restrict__ dst, int* __restrict__ bh,
                                   float* __restrict__ sums, float* __restrict__ cntg) {
    __shared__ int lh[NB];
    int t = threadIdx.x;
    if (blockIdx.x == 0) {
        for (int i = t; i < N_GRAPHS * HIDDEN; i += 256) sums[i] = 0.0f;
        if (t < N_GRAPHS) cntg[t] = 0.0f;
    }
    for (int i = t; i < NB; i += 256) lh[i] = 0;
    __syncthreads();
    int base = blockIdx.x * ECHUNK;
    for (int i = t; i < ECHUNK; i += 256) {
        int e = base + i;
        if (e < N_EDGES) {
            int d = dst[e];
            if ((unsigned)d < N_NODES) atomicAdd(&lh[d >> BSHIFT], 1);
        }
    }
    __syncthreads();
    for (int i = t; i < NB; i += 256) bh[i * EB + blockIdx.x] = lh[i];
}

__global__ void scan_part_kernel(const int* __restrict__ a, int* __restrict__ bsum) {
    __shared__ int s[256];
    int t = threadIdx.x;
    int ebase = blockIdx.x * SCHUNK + t * 4;
    int v = 0;
    if (ebase + 3 < SLEN) {
        int4 c = *(const int4*)&a[ebase];
        v = c.x + c.y + c.z + c.w;
    } else {
        for (int k = 0; k < 4; k++) {
            int i = ebase + k;
            if (i < SLEN) v += a[i];
        }
    }
    s[t] = v;
    __syncthreads();
    for (int off = 128; off > 0; off >>= 1) {
        if (t < off) s[t] += s[t + off];
        __syncthreads();
    }
    if (t == 0) bsum[blockIdx.x] = s[0];
}

__global__ void scan_apply_kernel(const int* __restrict__ a, const int* __restrict__ bsum,
                                  int* __restrict__ boff) {
    __shared__ int sb[256];
    __shared__ int st[256];
    int t = threadIdx.x;
    sb[t] = (t < NSB) ? bsum[t] : 0;
    __syncthreads();
    for (int off = 1; off < 256; off <<= 1) {
        int u = (t >= off) ? sb[t - off] : 0;
        __syncthreads();
        sb[t] += u;
        __syncthreads();
    }
    int blockOff = (blockIdx.x > 0) ? sb[blockIdx.x - 1] : 0;

    int ebase = blockIdx.x * SCHUNK + t * 4;
    int c0 = 0, c1 = 0, c2 = 0, c3 = 0;
    bool full = (ebase + 3 < SLEN);
    if (full) {
        int4 c = *(const int4*)&a[ebase];
        c0 = c.x; c1 = c.y; c2 = c.z; c3 = c.w;
    } else {
        if (ebase < SLEN) c0 = a[ebase];
        if (ebase + 1 < SLEN) c1 = a[ebase + 1];
        if (ebase + 2 < SLEN) c2 = a[ebase + 2];
    }
    int tsum = c0 + c1 + c2 + c3;
    st[t] = tsum;
    __syncthreads();
    for (int off = 1; off < 256; off <<= 1) {
        int u = (t >= off) ? st[t - off] : 0;
        __syncthreads();
        st[t] += u;
        __syncthreads();
    }
    int p = blockOff + st[t] - tsum;
    if (full) {
        int4 o;
        o.x = p; o.y = p + c0; o.z = p + c0 + c1; o.w = p + c0 + c1 + c2;
        *(int4*)&boff[ebase] = o;
    } else {
        if (ebase < SLEN) boff[ebase] = p;
        if (ebase + 1 < SLEN) boff[ebase + 1] = p + c0;
        if (ebase + 2 < SLEN) boff[ebase + 2] = p + c0 + c1;
        if (ebase + 3 < SLEN) boff[ebase + 3] = p + c0 + c1 + c2;
    }
}

__global__ void bucket_scatter_kernel(const int* __restrict__ src, const int* __restrict__ dst,
                                      const int* __restrict__ boff, int2* __restrict__ pairs) {
    __shared__ int lcnt[NB];
    __shared__ int goff[NB];
    int t = threadIdx.x;
    for (int i = t; i < NB; i += 256) {
        lcnt[i] = 0;
        goff[i] = boff[i * EB + blockIdx.x];
    }
    __syncthreads();
    int base = blockIdx.x * ECHUNK;
    for (int i = t; i < ECHUNK; i += 256) {
        int e = base + i;
        if (e < N_EDGES) {
            int d = dst[e];
            if ((unsigned)d < N_NODES) {
                int b = d >> BSHIFT;
                int r = atomicAdd(&lcnt[b], 1);
                int2 p;
                p.x = src[e];
                p.y = d;
                pairs[goff[b] + r] = p;
            }
        }
    }
}

__global__ void bucket_csr_kernel(const int2* __restrict__ pairs, const int* __restrict__ boff,
                                  int* __restrict__ csr, int* __restrict__ rowptr,
                                  int* __restrict__ cnt_node, float* __restrict__ dinv) {
    __shared__ int lcnt[BNODES];
    __shared__ int ls[BNODES];
    __shared__ int lrow[BNODES];
    int b = blockIdx.x;
    int t = threadIdx.x;
    if (t < BNODES) lcnt[t] = 0;
    __syncthreads();
    int bstart = boff[b * EB];
    int bend = (b + 1 < NB) ? boff[(b + 1) * EB] : N_EDGES;
    int K = bend - bstart;
    int myn[MAXK], myr[MAXK], mys[MAXK];
#pragma unroll
    for (int k = 0; k < MAXK; k++) {
        int i = k * 256 + t;
        if (i < K) {
            int2 p = pairs[bstart + i];
            int nl = p.y & (BNODES - 1);
            mys[k] = p.x;
            myn[k] = nl;
            myr[k] = atomicAdd(&lcnt[nl], 1);
        }
    }
    __syncthreads();
    if (t < BNODES) ls[t] = lcnt[t];
    __syncthreads();
    for (int off = 1; off < BNODES; off <<= 1) {
        int u = (t >= off && t < BNODES) ? ls[t - off] : 0;
        __syncthreads();
        if (t < BNODES) ls[t] += u;
        __syncthreads();
    }
    if (t < BNODES) {
        int ex = ls[t] - lcnt[t];
        lrow[t] = ex;
        int n = b * BNODES + t;
        if (n < N_NODES) {
            rowptr[n] = bstart + ex;
            cnt_node[n] = lcnt[t];
            dinv[n] = rsqrtf((float)(lcnt[t] + 1));  // +1 self-loop
        }
    }
    __syncthreads();
#pragma unroll
    for (int k = 0; k < MAXK; k++) {
        int i = k * 256 + t;
        if (i < K) csr[bstart + lrow[myn[k]] + myr[k]] = mys[k];
    }
}

// ---------------- fused layer 1: aggregate(x) -> LDS -> linear+relu -> h1' (bf16, pre-scaled) ----------------

// Phase A: 4 lanes/edge, float4 (4 ch) per lane, 16 edges/wave in flight.
// Phase B: gemm1 via transposed W1 (float4 LDS reads). Output h1' = dinv[n]*relu(.).
__global__ void fused_l1_kernel(const float* __restrict__ x, const int* __restrict__ csr_src,
                                const int* __restrict__ rowptr, const int* __restrict__ cnt,
                                const float* __restrict__ dinv, const float* __restrict__ W,
                                const float* __restrict__ b, __hip_bfloat16* __restrict__ h) {
    __shared__ float sWT[HIDDEN * 20];     // W1^T: [c][k], stride 20 (16B-aligned), 5 KB
    __shared__ float sx[16 * IN_CH];       // 1 KB
    int t = threadIdx.x;
    for (int i = t; i < IN_CH * HIDDEN; i += 256) {
        int k = i >> 6, c = i & 63;
        sWT[c * 20 + k] = W[i];
    }

    int n0 = blockIdx.x * 16;
    int w = t >> 6;
    int lane = t & 63;
    int e4 = lane >> 2;          // edge slot 0..15
    int cc = (lane & 3) * 4;     // channel quad
    for (int q = 0; q < 4; q++) {
        int row = w * 4 + q;
        int n = n0 + row;
        if (n >= N_NODES) break;
        int len = cnt[n];
        int start = rowptr[n];
        float4 acc = make_float4(0.f, 0.f, 0.f, 0.f);
        for (int i = e4; i < len; i += 16) {
            int s = csr_src[start + i];
            float dv = dinv[s];
            float4 xv = *(const float4*)&x[s * IN_CH + cc];
            acc.x += dv * xv.x; acc.y += dv * xv.y; acc.z += dv * xv.z; acc.w += dv * xv.w;
        }
#pragma unroll
        for (int m = 4; m <= 32; m <<= 1) {
            acc.x += __shfl_xor(acc.x, m, 64);
            acc.y += __shfl_xor(acc.y, m, 64);
            acc.z += __shfl_xor(acc.z, m, 64);
            acc.w += __shfl_xor(acc.w, m, 64);
        }
        if (lane < 4) {
            float dn = dinv[n];
            float4 xs = *(const float4*)&x[n * IN_CH + cc];
            float4 v;
            v.x = dn * acc.x + dn * dn * xs.x;
            v.y = dn * acc.y + dn * dn * xs.y;
            v.z = dn * acc.z + dn * dn * xs.z;
            v.w = dn * acc.w + dn * dn * xs.w;
            *(float4*)&sx[row * IN_CH + cc] = v;
        }
    }
    __syncthreads();

    int r = w;
    int c = t & 63;
    float bias = b[c];
#pragma unroll
    for (int nb = 0; nb < 4; nb++) {
        int row = nb * 4 + r;
        int n = n0 + row;
        if (n >= N_NODES) continue;
        float acc = bias;
#pragma unroll
        for (int k4 = 0; k4 < IN_CH; k4 += 4) {
            float4 a = *(const float4*)&sx[row * IN_CH + k4];
            float4 wv = *(const float4*)&sWT[c * 20 + k4];
            acc += a.x * wv.x + a.y * wv.y + a.z * wv.z + a.w * wv.w;
        }
        float v = acc > 0.0f ? acc : 0.0f;
        h[n * HIDDEN + c] = __float2bfloat16(dinv[n] * v);   // pre-scaled h1'
    }
}

// ---------------- fused layer 2: aggregate(h1') -> LDS -> linear+relu -> pool ----------------

// Phase A: 16 lanes/edge, ushort4 (4 bf16 ch) per lane, 4 edges/wave, 2-way unroll.
// agg = dn * (sum_s h1'[s] + h1'[n])  -- no per-edge dinv.
__global__ void fused_l2_kernel(const __hip_bfloat16* __restrict__ h, const int* __restrict__ csr_src,
                                const int* __restrict__ rowptr, const int* __restrict__ cnt,
                                const float* __restrict__ dinv, const float* __restrict__ W,
                                const float* __restrict__ b, const int* __restrict__ batch,
                                float* __restrict__ sums, float* __restrict__ cntg) {
    __shared__ float sWT[HIDDEN * WT_LD];  // W2^T: [c][k], stride 68, 17.4 KB
    __shared__ float sagg[16 * HIDDEN];    // 4 KB: agg rows, then h2 rows
    __shared__ float sred[4 * HIDDEN];     // 1 KB: pool fast-path reduce
    int t = threadIdx.x;
    for (int i = t; i < HIDDEN * HIDDEN; i += 256) {
        int k = i >> 6, c = i & 63;
        sWT[c * WT_LD + k] = W[i];
    }

    int n0 = blockIdx.x * 16;
    int w = t >> 6;
    int lane = t & 63;
    int e4 = lane >> 4;          // edge slot 0..3
    int cc = (lane & 15) * 4;    // channel quad
    const unsigned short* hu = (const unsigned short*)h;

    for (int q = 0; q < 4; q++) {
        int row = w * 4 + q;
        int n = n0 + row;
        if (n >= N_NODES) break;
        int len = cnt[n];
        int start = rowptr[n];
        float4 acc = make_float4(0.f, 0.f, 0.f, 0.f);
        int i = e4;
        for (; i + 4 < len; i += 8) {   // 2-way unroll: 8 gathers in flight per wave
            int s0 = csr_src[start + i];
            int s1 = csr_src[start + i + 4];
            ushort4 a = *(const ushort4*)&hu[s0 * HIDDEN + cc];
            ushort4 bq = *(const ushort4*)&hu[s1 * HIDDEN + cc];
            acc.x += bf2f(a.x) + bf2f(bq.x);
            acc.y += bf2f(a.y) + bf2f(bq.y);
            acc.z += bf2f(a.z) + bf2f(bq.z);
            acc.w += bf2f(a.w) + bf2f(bq.w);
        }
        for (; i < len; i += 4) {
            int s0 = csr_src[start + i];
            ushort4 a = *(const ushort4*)&hu[s0 * HIDDEN + cc];
            acc.x += bf2f(a.x);
            acc.y += bf2f(a.y);
            acc.z += bf2f(a.z);
            acc.w += bf2f(a.w);
        }
        acc.x += __shfl_xor(acc.x, 16, 64);
        acc.y += __shfl_xor(acc.y, 16, 64);
        acc.z += __shfl_xor(acc.z, 16, 64);
        acc.w += __shfl_xor(acc.w, 16, 64);
        acc.x += __shfl_xor(acc.x, 32, 64);
        acc.y += __shfl_xor(acc.y, 32, 64);
        acc.z += __shfl_xor(acc.z, 32, 64);
        acc.w += __shfl_xor(acc.w, 32, 64);
        if (lane < 16) {
            ushort4 sv = *(const ushort4*)&hu[n * HIDDEN + cc];
            float dn = dinv[n];
            float4 v;
            v.x = dn * (acc.x + bf2f(sv.x));
            v.y = dn * (acc.y + bf2f(sv.y));
            v.z = dn * (acc.z + bf2f(sv.z));
            v.w = dn * (acc.w + bf2f(sv.w));
            *(float4*)&sagg[row * HIDDEN + cc] = v;
        }
    }
    __syncthreads();

    // Phase B: gemm2 + bias + relu, float4 LDS reads both operands
    int r = w;
    int c = t & 63;
    float bias = b[c];
    float vout[4];
#pragma unroll
    for (int nb = 0; nb < 4; nb++) {
        int row = nb * 4 + r;
        int n = n0 + row;
        vout[nb] = 0.0f;
        if (n >= N_NODES) continue;
        float acc = bias;
#pragma unroll
        for (int k4 = 0; k4 < HIDDEN; k4 += 4) {
            float4 a = *(const float4*)&sagg[row * HIDDEN + k4];
            float4 wv = *(const float4*)&sWT[c * WT_LD + k4];
            acc += a.x * wv.x + a.y * wv.y + a.z * wv.z + a.w * wv.w;
        }
        vout[nb] = acc > 0.0f ? acc : 0.0f;
    }
    __syncthreads();

#pragma unroll
    for (int nb = 0; nb < 4; nb++) {
        int row = nb * 4 + r;
        if (n0 + row < N_NODES) sagg[row * HIDDEN + c] = vout[nb];
    }
    __syncthreads();

    // Phase C: pool (batch sorted -> tile usually one graph)
    int nlast = n0 + 15;
    if (nlast >= N_NODES) nlast = N_NODES - 1;
    int glo = batch[n0];
    int ghi = batch[nlast];
    if (glo == ghi) {
        float p = 0.0f;
#pragma unroll
        for (int q = 0; q < 4; q++) {
            int row = 4 * r + q;
            if (n0 + row < N_NODES) p += sagg[row * HIDDEN + c];
        }
        sred[r * HIDDEN + c] = p;
        __syncthreads();
        if (r == 0) {
            float v = sred[c] + sred[HIDDEN + c] + sred[2 * HIDDEN + c] + sred[3 * HIDDEN + c];
            atomicAdd(&sums[glo * HIDDEN + c], v);
            if (c == 0) atomicAdd(&cntg[glo], (float)(nlast - n0 + 1));
        }
    } else {
        int gcur = -1;
        float acc = 0.0f, ccnt = 0.0f;
        for (int q = 0; q < 4; q++) {
            int row = 4 * r + q;
            int n = n0 + row;
            if (n >= N_NODES) break;
            int g = batch[n];
            if ((unsigned)g >= N_GRAPHS) continue;
            if (g != gcur) {
                if (gcur >= 0) {
                    atomicAdd(&sums[gcur * HIDDEN + c], acc);
                    if (c == 0) atomicAdd(&cntg[gcur], ccnt);
                }
                gcur = g;
                acc = 0.0f;
                ccnt = 0.0f;
            }
            acc += sagg[row * HIDDEN + c];
            ccnt += 1.0f;
        }
        if (gcur >= 0) {
            atomicAdd(&sums[gcur * HIDDEN + c], acc);
            if (c == 0) atomicAdd(&cntg[gcur], ccnt);
        }
    }
}

// ---------------- head ----------------

__global__ void head_kernel(const float* __restrict__ sums, const float* __restrict__ cntg,
                            const float* __restrict__ Wc, const float* __restrict__ bc,
                            float* __restrict__ out) {
    int t = blockIdx.x * blockDim.x + threadIdx.x;
    if (t >= N_GRAPHS * OUT_CH) return;
    int g = t >> 1;
    int o = t & 1;
    float inv = 1.0f / fmaxf(cntg[g], 1.0f);
    float acc = bc[o];
#pragma unroll
    for (int k = 0; k < HIDDEN; k++) acc += sums[g * HIDDEN + k] * inv * Wc[k * OUT_CH + o];
    out[t] = acc;
}

// ---------------- launch ----------------

extern "C" void kernel_launch(void* const* d_in, const int* in_sizes, int n_in,
                              void* d_out, int out_size, void* d_ws, size_t ws_size,
                              hipStream_t stream) {
    const float* x  = (const float*)d_in[0];
    const int* ei   = (const int*)d_in[1];
    const int* bat  = (const int*)d_in[2];
    const float* W1 = (const float*)d_in[3];
    const float* b1 = (const float*)d_in[4];
    const float* W2 = (const float*)d_in[5];
    const float* b2 = (const float*)d_in[6];
    const float* Wc = (const float*)d_in[7];
    const float* bc = (const float*)d_in[8];
    float* out = (float*)d_out;

    const int* src = ei;
    const int* dst = ei + N_EDGES;

    char* ws = (char*)d_ws;
    size_t off = 0;
    auto carve = [&](size_t nbytes) {
        char* p = ws + off;
        off += (nbytes + 255) & ~(size_t)255;
        return p;
    };
    float* sums     = (float*)carve(N_GRAPHS * HIDDEN * sizeof(float));
    float* cntg     = (float*)carve(N_GRAPHS * sizeof(float));
    int*   bh       = (int*)carve((size_t)SLEN * sizeof(int));
    int*   bsum     = (int*)carve(NSB * sizeof(int));
    int*   boff     = (int*)carve((size_t)SLEN * sizeof(int));
    int2*  pairs    = (int2*)carve((size_t)N_EDGES * sizeof(int2));
    int*   csr      = (int*)carve((size_t)N_EDGES * sizeof(int));
    int*   rowptr   = (int*)carve(N_NODES * sizeof(int));
    int*   cnt_node = (int*)carve(N_NODES * sizeof(int));
    float* dinv     = (float*)carve(N_NODES * sizeof(float));
    __hip_bfloat16* bufA = (__hip_bfloat16*)carve((size_t)N_NODES * HIDDEN * sizeof(__hip_bfloat16));
    (void)ws_size;

    const int node16Blk = (N_NODES + 15) / 16;

    bucket_hist_kernel<<<EB, 256, 0, stream>>>(dst, bh, sums, cntg);
    scan_part_kernel<<<NSB, 256, 0, stream>>>(bh, bsum);
    scan_apply_kernel<<<NSB, 256, 0, stream>>>(bh, bsum, boff);
    bucket_scatter_kernel<<<EB, 256, 0, stream>>>(src, dst, boff, pairs);
    bucket_csr_kernel<<<NB, 256, 0, stream>>>(pairs, boff, csr, rowptr, cnt_node, dinv);

    fused_l1_kernel<<<node16Blk, 256, 0, stream>>>(x, csr, rowptr, cnt_node, dinv, W1, b1, bufA);
    fused_l2_kernel<<<node16Blk, 256, 0, stream>>>(bufA, csr, rowptr, cnt_node, dinv, W2, b2,
                                                   bat, sums, cntg);
    head_kernel<<<1, 256, 0, stream>>>(sums, cntg, Wc, bc, out);
}